// Round 1
// baseline (8830.630 us; speedup 1.0000x reference)
//
#include <hip/hip_runtime.h>
#include <cmath>

// ---------------------------------------------------------------------------
// Model dims
//   H=256 HID=128 V=50000 LV=200 N=512 L=64 M=64 C=4 T=8 K=8
// ---------------------------------------------------------------------------

__device__ __forceinline__ float sigf(float x) { return 1.f / (1.f + expf(-x)); }

// ---------------------------------------------------------------------------
// whh (384x128) -> whhT (128x384), batched (mats contiguous)
// ---------------------------------------------------------------------------
__global__ __launch_bounds__(256) void k_transpose_whh(const float* __restrict__ src,
                                                       float* __restrict__ dst) {
  int b = blockIdx.x;
  const float* s = src + (size_t)b * 49152;
  float* d = dst + (size_t)b * 49152;
  for (int i = threadIdx.x; i < 49152; i += 256) {
    int j = i >> 7;       // 0..383  (gate row)
    int k = i & 127;      // 0..127
    d[k * 384 + j] = s[i];
  }
}

// ---------------------------------------------------------------------------
// W_comb[j][k] : k<256 -> uiou[j][k] ; k>=256 -> wiou[j][k-256]   (768x512)
// ---------------------------------------------------------------------------
__global__ __launch_bounds__(256) void k_build_wcomb(const float* __restrict__ uiou,
                                                     const float* __restrict__ wiou,
                                                     float* __restrict__ wc) {
  int i = blockIdx.x * 256 + threadIdx.x;  // < 768*512
  if (i >= 768 * 512) return;
  int j = i >> 9;
  int k = i & 511;
  wc[i] = (k < 256) ? uiou[j * 256 + k] : wiou[j * 256 + (k - 256)];
}

// ---------------------------------------------------------------------------
// zero nei_sum (512x256), deg (512 ints), flag
// ---------------------------------------------------------------------------
__global__ __launch_bounds__(256) void k_zero_misc(float* __restrict__ nei_sum,
                                                   int* __restrict__ deg,
                                                   int* __restrict__ flag) {
  int i = blockIdx.x * 256 + threadIdx.x;
  if (i < 512 * 256) nei_sum[i] = 0.f;
  if (i < 512) deg[i] = 0;
  if (i == 0) *flag = 0;
}

// ---------------------------------------------------------------------------
// bool-mask dtype detector: if buffer is byte-packed bools, some 32-bit word
// in the first 32768 words (=131072 bytes, safe either way) exceeds 1.
// ---------------------------------------------------------------------------
__global__ __launch_bounds__(256) void k_mask_detect(const unsigned* __restrict__ raw,
                                                     int* __restrict__ flag) {
  int i = blockIdx.x * 256 + threadIdx.x;
  if (i < 32768) {
    if (raw[i] > 1u) atomicOr(flag, 1);
  }
}

__global__ __launch_bounds__(256) void k_mask_convert(const void* __restrict__ raw,
                                                      const int* __restrict__ flag,
                                                      int* __restrict__ msk) {
  int i = blockIdx.x * 256 + threadIdx.x;  // < 131072
  if (i >= 512 * 64 * 4) return;
  int v;
  if (*flag) v = ((const unsigned char*)raw)[i] != 0;
  else       v = ((const int*)raw)[i] != 0;
  msk[i] = v;
}

// ---------------------------------------------------------------------------
// Generic fp32 GEMM:  C[r][j] = sum_k Arow(r)[k] * W[j][k] (+bias[j]) (relu?)
//   Arow(r) = A + (ridx? ridx[r] : r) * rstride
//   128x128 tile, 256 threads, 8x8 micro, K chunked by 8.
//   Requires R%128==0, J%128==0, K%8==0.
// ---------------------------------------------------------------------------
__global__ __launch_bounds__(256) void k_gemm128(const float* __restrict__ A,
                                                 const int* __restrict__ ridx,
                                                 int rstride,
                                                 const float* __restrict__ W,
                                                 const float* __restrict__ bias,
                                                 float* __restrict__ C,
                                                 int R, int K, int J, int relu) {
  __shared__ float As[8][132];
  __shared__ float Ws[8][132];
  int njt = J >> 7;
  int rt = blockIdx.x / njt;
  int jt = blockIdx.x % njt;
  int tid = threadIdx.x;
  int tx = tid & 15, ty = tid >> 4;

  int row2 = tid >> 1;         // 0..127
  int kq = (tid & 1) * 4;      // 0 or 4
  int gr = rt * 128 + row2;
  const float* arow = A + (size_t)(ridx ? ridx[gr] : gr) * rstride;
  const float* wrow = W + (size_t)(jt * 128 + row2) * K;

  float acc[8][8];
#pragma unroll
  for (int i = 0; i < 8; ++i)
#pragma unroll
    for (int j = 0; j < 8; ++j) acc[i][j] = 0.f;

  for (int k0 = 0; k0 < K; k0 += 8) {
    float4 av = *(const float4*)(arow + k0 + kq);
    float4 wv = *(const float4*)(wrow + k0 + kq);
    __syncthreads();
    As[kq + 0][row2] = av.x; As[kq + 1][row2] = av.y;
    As[kq + 2][row2] = av.z; As[kq + 3][row2] = av.w;
    Ws[kq + 0][row2] = wv.x; Ws[kq + 1][row2] = wv.y;
    Ws[kq + 2][row2] = wv.z; Ws[kq + 3][row2] = wv.w;
    __syncthreads();
#pragma unroll
    for (int kk = 0; kk < 8; ++kk) {
      float a[8], b[8];
      *(float4*)&a[0] = *(const float4*)&As[kk][ty * 8];
      *(float4*)&a[4] = *(const float4*)&As[kk][ty * 8 + 4];
      *(float4*)&b[0] = *(const float4*)&Ws[kk][tx * 8];
      *(float4*)&b[4] = *(const float4*)&Ws[kk][tx * 8 + 4];
#pragma unroll
      for (int i = 0; i < 8; ++i)
#pragma unroll
        for (int j = 0; j < 8; ++j) acc[i][j] += a[i] * b[j];
    }
  }

  int colbase = jt * 128 + tx * 8;
  float bb[8];
#pragma unroll
  for (int j = 0; j < 8; ++j) bb[j] = bias ? bias[colbase + j] : 0.f;
#pragma unroll
  for (int i = 0; i < 8; ++i) {
    int row = rt * 128 + ty * 8 + i;
    float* crow = C + (size_t)row * J + colbase;
#pragma unroll
    for (int j = 0; j < 8; ++j) {
      float v = acc[i][j] + bb[j];
      if (relu) v = fmaxf(v, 0.f);
      crow[j] = v;
    }
  }
}

// ---------------------------------------------------------------------------
// GRU recurrence. One block = 8 samples, one direction.
//   256 threads: j = tid&127 handles gate rows (j, 128+j, 256+j); kh=tid>>7
//   splits the 128-d h dot into two 64 halves (LDS reduce).
//   gi:  rows (n*L+t)*768, dir offset d*384 (bih already added by GEMM)
//   whhT: [128][384] per dir (base + d*49152); bhh: base + d*384
//   out: [n][t][256], dir writes d*128 + j
// ---------------------------------------------------------------------------
__global__ __launch_bounds__(256) void k_gru(const float* __restrict__ gi,
                                             const float* __restrict__ whhT2,
                                             const float* __restrict__ bhh2,
                                             float* __restrict__ out,
                                             int N, int L) {
  __shared__ float hsh[8][132];
  __shared__ float part[8][3][128];
  int tid = threadIdx.x;
  int j = tid & 127, kh = tid >> 7;
  int d = blockIdx.y;
  int n0 = blockIdx.x * 8;
  const float* whhT = whhT2 + (size_t)d * 49152;
  const float* bhh = bhh2 + d * 384;

  for (int i = tid; i < 8 * 132; i += 256) ((float*)hsh)[i] = 0.f;
  __syncthreads();

  int t = d ? (L - 1) : 0;
  int dt = d ? -1 : 1;
  int doff = d * 384;

  for (int step = 0; step < L; ++step, t += dt) {
    float ar[8], az[8], an[8];
#pragma unroll
    for (int s = 0; s < 8; ++s) { ar[s] = 0.f; az[s] = 0.f; an[s] = 0.f; }
    int kbase = kh * 64;
#pragma unroll 4
    for (int kc = 0; kc < 64; kc += 4) {
      int k0 = kbase + kc;
      float wr0, wr1, wr2, wr3, wz0, wz1, wz2, wz3, wn0, wn1, wn2, wn3;
      {
        const float* w0 = whhT + (size_t)(k0 + 0) * 384;
        const float* w1 = whhT + (size_t)(k0 + 1) * 384;
        const float* w2 = whhT + (size_t)(k0 + 2) * 384;
        const float* w3 = whhT + (size_t)(k0 + 3) * 384;
        wr0 = w0[j];       wr1 = w1[j];       wr2 = w2[j];       wr3 = w3[j];
        wz0 = w0[128 + j]; wz1 = w1[128 + j]; wz2 = w2[128 + j]; wz3 = w3[128 + j];
        wn0 = w0[256 + j]; wn1 = w1[256 + j]; wn2 = w2[256 + j]; wn3 = w3[256 + j];
      }
#pragma unroll
      for (int s = 0; s < 8; ++s) {
        float4 hv = *(const float4*)&hsh[s][k0];
        ar[s] += hv.x * wr0 + hv.y * wr1 + hv.z * wr2 + hv.w * wr3;
        az[s] += hv.x * wz0 + hv.y * wz1 + hv.z * wz2 + hv.w * wz3;
        an[s] += hv.x * wn0 + hv.y * wn1 + hv.z * wn2 + hv.w * wn3;
      }
    }
    if (kh == 1) {
#pragma unroll
      for (int s = 0; s < 8; ++s) {
        part[s][0][j] = ar[s];
        part[s][1][j] = az[s];
        part[s][2][j] = an[s];
      }
    }
    __syncthreads();
    if (kh == 0) {
      float b_r = bhh[j], b_z = bhh[128 + j], b_n = bhh[256 + j];
#pragma unroll
      for (int s = 0; s < 8; ++s) {
        int n = n0 + s;
        const float* g = gi + (size_t)(n * L + t) * 768 + doff;
        float hr = ar[s] + part[s][0][j] + b_r;
        float hz = az[s] + part[s][1][j] + b_z;
        float hn = an[s] + part[s][2][j] + b_n;
        float r = sigf(g[j] + hr);
        float z = sigf(g[128 + j] + hz);
        float nn = tanhf(g[256 + j] + r * hn);
        float hnew = (1.f - z) * nn + z * hsh[s][j];
        hsh[s][j] = hnew;
        out[(size_t)(n * L + t) * 256 + d * 128 + j] = hnew;
      }
    }
    __syncthreads();
  }
}

// ---------------------------------------------------------------------------
// Attention pool. block = 256 threads, one block per n.
//   scores from score_src (row: n*s_ns + l*s_ls), values from val_src.
// ---------------------------------------------------------------------------
__global__ __launch_bounds__(256) void k_attn_pool(const float* __restrict__ score_src,
                                                   int s_ns, int s_ls,
                                                   const float* __restrict__ val_src,
                                                   int v_ns, int v_ls,
                                                   const float* __restrict__ w,
                                                   const float* __restrict__ bptr,
                                                   float* __restrict__ dst,
                                                   int dst_stride, int L) {
  __shared__ float wts[64];
  int n = blockIdx.x;
  int tid = threadIdx.x;
  if (tid < 64) {
    float a = -INFINITY;
    if (tid < L) {
      const float* row = score_src + (size_t)n * s_ns + (size_t)tid * s_ls;
      float s = bptr[0];
      for (int h = 0; h < 256; h += 4) {
        float4 v = *(const float4*)(row + h);
        float4 wv = *(const float4*)(w + h);
        s += v.x * wv.x + v.y * wv.y + v.z * wv.z + v.w * wv.w;
      }
      a = s;
    }
    float mx = a;
#pragma unroll
    for (int off = 32; off; off >>= 1) mx = fmaxf(mx, __shfl_xor(mx, off));
    float e = (tid < L) ? expf(a - mx) : 0.f;
    float ss = e;
#pragma unroll
    for (int off = 32; off; off >>= 1) ss += __shfl_xor(ss, off);
    if (tid < L) wts[tid] = e / ss;
  }
  __syncthreads();
  float acc = 0.f;
  for (int l = 0; l < L; ++l)
    acc += wts[l] * val_src[(size_t)n * v_ns + (size_t)l * v_ls + tid];
  dst[(size_t)n * dst_stride + tid] = acc;
}

// ---------------------------------------------------------------------------
// xn[n][m][h] = 0.5*label_tab[lbl][h] + 0.5*mean_t tok_tab[id][h]
// ---------------------------------------------------------------------------
__global__ __launch_bounds__(256) void k_xn(const float* __restrict__ label_tab,
                                            const float* __restrict__ tok_tab,
                                            const int* __restrict__ lbl_ids,
                                            const int* __restrict__ tok_ids,
                                            float* __restrict__ xn) {
  int nm = blockIdx.x;  // 0..32767
  int h = threadIdx.x;
  const int* tids = tok_ids + (size_t)nm * 8;
  float s = 0.f;
#pragma unroll
  for (int t = 0; t < 8; ++t) s += tok_tab[(size_t)tids[t] * 256 + h];
  xn[(size_t)nm * 256 + h] = 0.5f * label_tab[(size_t)lbl_ids[nm] * 256 + h] + 0.0625f * s;
}

// ---------------------------------------------------------------------------
// TreeLSTM step GEMMs (fused child gather).  grid = 224 blocks:
//   b<96:  iou tile (rt=b/12, jt=b%12): iou[n][j] = biou[j]
//           + sum_{k<256} hsum[n][k]*uiou[j][k] + sum xn[n][m][k]*wiou[j][k]
//           via A=[hsum|xn] (K=512) and W_comb.
//   else:  fg tile: fgh[(n,c)][j] = sum_k ch_h[n][c][k]*uf[j][k]
//   64x64 tile, 256 threads, 4x4 micro, K chunked by 16.
// ---------------------------------------------------------------------------
__global__ __launch_bounds__(256) void k_tl_gemm(const float* __restrict__ h_arr,
                                                 const float* __restrict__ xn,
                                                 const int* __restrict__ ch,
                                                 const int* __restrict__ msk,
                                                 const float* __restrict__ wcomb,
                                                 const float* __restrict__ uf,
                                                 const float* __restrict__ biou,
                                                 float* __restrict__ iou,
                                                 float* __restrict__ fgh,
                                                 int m) {
  __shared__ float As[16][68];
  __shared__ float Ws[16][68];
  __shared__ int chs[64][4];
  __shared__ float msks[64][4];
  int b = blockIdx.x;
  int tid = threadIdx.x;
  bool isIou = b < 96;
  int rt, jt, K;
  const float* W;
  if (isIou) { rt = b / 12; jt = b % 12; K = 512; W = wcomb; }
  else { int bb = b - 96; rt = bb / 4; jt = bb % 4; K = 256; W = uf; }

  if (isIou) {
    int r = tid >> 2, c = tid & 3;  // 64 rows x 4 children
    int n = rt * 64 + r;
    chs[r][c] = ch[((size_t)(n * 64 + m)) * 4 + c];
    msks[r][c] = msk[((size_t)(n * 64 + m)) * 4 + c] ? 1.f : 0.f;
  } else {
    if (tid < 64) {
      int rr = rt * 64 + tid;
      int n = rr >> 2, c = rr & 3;
      chs[tid][0] = ch[((size_t)(n * 64 + m)) * 4 + c];
      msks[tid][0] = msk[((size_t)(n * 64 + m)) * 4 + c] ? 1.f : 0.f;
    }
  }
  __syncthreads();

  int tx = tid & 15, ty = tid >> 4;
  int row = tid >> 2;          // staging row 0..63
  int kq = (tid & 3) * 4;      // 0,4,8,12

  float acc[4][4];
#pragma unroll
  for (int i = 0; i < 4; ++i)
#pragma unroll
    for (int j = 0; j < 4; ++j) acc[i][j] = 0.f;

  const float* wrow = W + (size_t)(jt * 64 + row) * K;

  for (int k0 = 0; k0 < K; k0 += 16) {
    float av[4];
#pragma unroll
    for (int i = 0; i < 4; ++i) {
      int k = k0 + kq + i;
      float val;
      if (isIou) {
        int gn = rt * 64 + row;
        if (k < 256) {
          val = 0.f;
#pragma unroll
          for (int c = 0; c < 4; ++c) {
            if (msks[row][c] != 0.f)
              val += h_arr[((size_t)chs[row][c] * 512 + gn) * 256 + k];
          }
        } else {
          val = xn[((size_t)gn * 64 + m) * 256 + (k - 256)];
        }
      } else {
        int rr = rt * 64 + row;
        int n = rr >> 2;
        val = (msks[row][0] != 0.f)
                ? h_arr[((size_t)chs[row][0] * 512 + n) * 256 + k]
                : 0.f;
      }
      av[i] = val;
    }
    float4 wv = *(const float4*)(wrow + k0 + kq);
    __syncthreads();
#pragma unroll
    for (int i = 0; i < 4; ++i) As[kq + i][row] = av[i];
    Ws[kq + 0][row] = wv.x; Ws[kq + 1][row] = wv.y;
    Ws[kq + 2][row] = wv.z; Ws[kq + 3][row] = wv.w;
    __syncthreads();
#pragma unroll
    for (int kk = 0; kk < 16; ++kk) {
      float a[4], bv[4];
      *(float4*)&a[0] = *(const float4*)&As[kk][ty * 4];
      *(float4*)&bv[0] = *(const float4*)&Ws[kk][tx * 4];
#pragma unroll
      for (int i = 0; i < 4; ++i)
#pragma unroll
        for (int j = 0; j < 4; ++j) acc[i][j] += a[i] * bv[j];
    }
  }

  int colbase = jt * 64 + tx * 4;
  if (isIou) {
    float bb[4];
#pragma unroll
    for (int j = 0; j < 4; ++j) bb[j] = biou[colbase + j];
#pragma unroll
    for (int i = 0; i < 4; ++i) {
      int n = rt * 64 + ty * 4 + i;
      float* crow = iou + (size_t)n * 768 + colbase;
#pragma unroll
      for (int j = 0; j < 4; ++j) crow[j] = acc[i][j] + bb[j];
    }
  } else {
#pragma unroll
    for (int i = 0; i < 4; ++i) {
      int rr = rt * 64 + ty * 4 + i;
      float* crow = fgh + (size_t)rr * 256 + colbase;
#pragma unroll
      for (int j = 0; j < 4; ++j) crow[j] = acc[i][j];
    }
  }
}

// ---------------------------------------------------------------------------
// TreeLSTM combine: per (n,h).
// ---------------------------------------------------------------------------
__global__ __launch_bounds__(256) void k_tl_combine(const float* __restrict__ iou,
                                                    const float* __restrict__ fgh,
                                                    const float* __restrict__ xf,
                                                    const int* __restrict__ ch,
                                                    const int* __restrict__ msk,
                                                    float* __restrict__ h_arr,
                                                    float* __restrict__ c_arr,
                                                    int m) {
  int n = blockIdx.x, h = threadIdx.x;
  float iv = sigf(iou[(size_t)n * 768 + h]);
  float ov = sigf(iou[(size_t)n * 768 + 256 + h]);
  float uv = tanhf(iou[(size_t)n * 768 + 512 + h]);
  const int* chp = ch + ((size_t)(n * 64 + m)) * 4;
  const int* mkp = msk + ((size_t)(n * 64 + m)) * 4;
  float xfv = xf[((size_t)(n * 64 + m)) * 256 + h];
  float cs = 0.f;
#pragma unroll
  for (int c = 0; c < 4; ++c) {
    if (mkp[c]) {
      float cc = c_arr[((size_t)chp[c] * 512 + n) * 256 + h];
      float fg = sigf(xfv + fgh[((size_t)(n * 4 + c)) * 256 + h]);
      cs += fg * cc;
    }
  }
  float cn = iv * uv + cs;
  float hn = ov * tanhf(cn);
  h_arr[((size_t)m * 512 + n) * 256 + h] = hn;
  c_arr[((size_t)m * 512 + n) * 256 + h] = cn;
}

// ---------------------------------------------------------------------------
// Graph kernels
// ---------------------------------------------------------------------------
__global__ __launch_bounds__(256) void k_edge_deg(const int* __restrict__ edges,
                                                  int* __restrict__ deg, int E) {
  int i = blockIdx.x * 256 + threadIdx.x;
  if (i < E) {
    atomicAdd(&deg[edges[2 * i]], 1);
    atomicAdd(&deg[edges[2 * i + 1]], 1);
  }
}

__global__ __launch_bounds__(256) void k_nei(const int* __restrict__ edges,
                                             const float* __restrict__ x,
                                             float* __restrict__ nei_sum) {
  int e = blockIdx.x, h = threadIdx.x;
  int a = edges[2 * e], b = edges[2 * e + 1];
  atomicAdd(&nei_sum[(size_t)a * 256 + h], x[(size_t)b * 256 + h]);
  atomicAdd(&nei_sum[(size_t)b * 256 + h], x[(size_t)a * 256 + h]);
}

__global__ __launch_bounds__(256) void k_xcat(const float* __restrict__ x,
                                              const float* __restrict__ nei_sum,
                                              const int* __restrict__ deg,
                                              float* __restrict__ xcat) {
  int n = blockIdx.x, h = threadIdx.x;
  xcat[(size_t)n * 512 + h] = x[(size_t)n * 256 + h];
  float d = fmaxf((float)deg[n], 1.f);
  xcat[(size_t)n * 512 + 256 + h] = nei_sum[(size_t)n * 256 + h] / d;
}

__global__ __launch_bounds__(256) void k_spmm_self(const float* __restrict__ y,
                                                   const int* __restrict__ deg,
                                                   float* __restrict__ ob) {
  int n = blockIdx.x, h = threadIdx.x;
  float dis2 = 1.f / (float)(deg[n] + 1);
  ob[(size_t)n * 256 + h] = dis2 * y[(size_t)n * 256 + h];
}

__global__ __launch_bounds__(256) void k_spmm_edge(const float* __restrict__ y,
                                                   const int* __restrict__ deg,
                                                   const int* __restrict__ edges,
                                                   float* __restrict__ ob) {
  int e = blockIdx.x, h = threadIdx.x;
  int a = edges[2 * e], b = edges[2 * e + 1];
  float w = (1.f / sqrtf((float)(deg[a] + 1))) * (1.f / sqrtf((float)(deg[b] + 1)));
  atomicAdd(&ob[(size_t)a * 256 + h], w * y[(size_t)b * 256 + h]);
  atomicAdd(&ob[(size_t)b * 256 + h], w * y[(size_t)a * 256 + h]);
}

__global__ __launch_bounds__(256) void k_relu_inplace(float* __restrict__ p) {
  int i = blockIdx.x * 256 + threadIdx.x;
  p[i] = fmaxf(p[i], 0.f);
}

__global__ __launch_bounds__(256) void k_final(const float* __restrict__ h2,
                                               const float* __restrict__ w1,
                                               const float* __restrict__ b1,
                                               const float* __restrict__ w2,
                                               const float* __restrict__ b2,
                                               float* __restrict__ outp) {
  __shared__ float gv[512];
  __shared__ float zz[256];
  int tid = threadIdx.x;
  float mn = 0.f, mx = -INFINITY;
  for (int n = 0; n < 512; ++n) {
    float v = h2[(size_t)n * 256 + tid];
    mn += v;
    mx = fmaxf(mx, v);
  }
  gv[tid] = mn / 512.f;
  gv[256 + tid] = mx;
  __syncthreads();
  float acc = b1[tid];
  for (int k = 0; k < 512; ++k) acc += gv[k] * w1[(size_t)tid * 512 + k];
  zz[tid] = fmaxf(acc, 0.f) * w2[tid];
  __syncthreads();
  for (int s = 128; s; s >>= 1) {
    if (tid < s) zz[tid] += zz[tid + s];
    __syncthreads();
  }
  if (tid == 0) outp[0] = zz[0] + b2[0];
}

// ---------------------------------------------------------------------------
// Host launch
// ---------------------------------------------------------------------------
extern "C" void kernel_launch(void* const* d_in, const int* in_sizes, int n_in,
                              void* d_out, int out_size, void* d_ws, size_t ws_size,
                              hipStream_t stream) {
  const int* seq_tokens    = (const int*)d_in[0];
  const int* ast_children  = (const int*)d_in[1];
  const void* ast_mask_raw = (const void*)d_in[2];
  const int* ast_label_ids = (const int*)d_in[3];
  const int* ast_tok_ids   = (const int*)d_in[4];
  const int* ctx_nei       = (const int*)d_in[5];
  const int* edges         = (const int*)d_in[6];
  const float* seq_emb  = (const float*)d_in[7];
  const float* seq_wih  = (const float*)d_in[8];
  const float* seq_whh  = (const float*)d_in[9];
  const float* seq_bih  = (const float*)d_in[10];
  const float* seq_bhh  = (const float*)d_in[11];
  const float* seq_pw   = (const float*)d_in[12];
  const float* seq_pb   = (const float*)d_in[13];
  const float* ctx_wih  = (const float*)d_in[14];
  const float* ctx_whh  = (const float*)d_in[15];
  const float* ctx_bih  = (const float*)d_in[16];
  const float* ctx_bhh  = (const float*)d_in[17];
  const float* ctx_pw   = (const float*)d_in[18];
  const float* ctx_pb   = (const float*)d_in[19];
  const float* ast_label_tab = (const float*)d_in[20];
  const float* ast_tok_tab   = (const float*)d_in[21];
  const float* ast_pw   = (const float*)d_in[22];
  const float* ast_pb   = (const float*)d_in[23];
  const float* tl_wiou  = (const float*)d_in[24];
  const float* tl_biou  = (const float*)d_in[25];
  const float* tl_uiou  = (const float*)d_in[26];
  const float* tl_wf    = (const float*)d_in[27];
  const float* tl_bf    = (const float*)d_in[28];
  const float* tl_uf    = (const float*)d_in[29];
  const float* fa_wih   = (const float*)d_in[30];
  const float* fa_whh   = (const float*)d_in[31];
  const float* fa_bih   = (const float*)d_in[32];
  const float* fa_bhh   = (const float*)d_in[33];
  const float* fa_aw    = (const float*)d_in[34];
  const float* fa_ab    = (const float*)d_in[35];
  const float* comb_w   = (const float*)d_in[36];
  const float* comb_b   = (const float*)d_in[37];
  const float* g1_w     = (const float*)d_in[38];
  const float* g1_b     = (const float*)d_in[39];
  const float* g2_w     = (const float*)d_in[40];
  const float* g2_b     = (const float*)d_in[41];
  const float* cls_w1   = (const float*)d_in[42];
  const float* cls_b1   = (const float*)d_in[43];
  const float* cls_w2   = (const float*)d_in[44];
  const float* cls_b2   = (const float*)d_in[45];
  float* outp = (float*)d_out;
  float* ws = (float*)d_ws;
  int E = in_sizes[6] / 2;

  // ----- workspace layout (floats) -----
  size_t off = 0;
  auto take = [&](size_t n) { size_t o = off; off += n; return o; };
  const size_t F_FEATS = take(512 * 5 * 256);   // 655360
  const size_t F_X     = take(512 * 256);
  const size_t F_X2    = take(512 * 256);
  const size_t F_Y     = take(512 * 256);
  const size_t F_H1    = take(512 * 256);
  const size_t F_H2    = take(512 * 256);
  const size_t F_XCAT  = take(512 * 512);
  const size_t F_NEI   = take(512 * 256);
  const size_t F_DEG   = take(512);
  const size_t F_FLAG  = take(16);
  const size_t F_MSK   = take(512 * 64 * 4);
  const size_t F_WHHT  = take(10 * 49152);
  const size_t F_WCOMB = take(768 * 512);
  const size_t F_IOU   = take(512 * 768);
  const size_t F_FGH   = take(2048 * 256);
  const size_t F_REGION = take(33554432);
  (void)ws_size;

  float* FEATS = ws + F_FEATS;
  float* X     = ws + F_X;
  float* X2    = ws + F_X2;
  float* Y     = ws + F_Y;
  float* H1    = ws + F_H1;
  float* H2    = ws + F_H2;
  float* XCAT  = ws + F_XCAT;
  float* NEI   = ws + F_NEI;
  int*   DEG   = (int*)(ws + F_DEG);
  int*   FLAG  = (int*)(ws + F_FLAG);
  int*   MSK   = (int*)(ws + F_MSK);
  float* WHHT  = ws + F_WHHT;
  float* WCOMB = ws + F_WCOMB;
  float* IOU   = ws + F_IOU;
  float* FGH   = ws + F_FGH;
  float* GI    = ws + F_REGION;                 // 25165824 (enc/ctx gi)
  float* OUT   = ws + F_REGION + 25165824;      // 8388608  (enc/ctx gru out)
  float* XN    = ws + F_REGION;                 // 8388608  (ast phase)
  float* XF    = XN + 8388608;
  float* HARR  = XF + 8388608;
  float* CARR  = HARR + 8388608;
  float* GIFA  = ws + F_REGION;                 // fa phase (after ast pool)
  float* OUTFA = GIFA + 1966080;

  auto gemm = [&](const float* A, const int* ridx, int rstride, const float* W,
                  const float* bias, float* C, int R, int K, int J, int relu) {
    dim3 g((R / 128) * (J / 128));
    k_gemm128<<<g, 256, 0, stream>>>(A, ridx, rstride, W, bias, C, R, K, J, relu);
  };

  // ---- prep ----
  k_transpose_whh<<<6, 256, 0, stream>>>(seq_whh, WHHT);
  k_transpose_whh<<<2, 256, 0, stream>>>(ctx_whh, WHHT + 6 * 49152);
  k_transpose_whh<<<2, 256, 0, stream>>>(fa_whh, WHHT + 8 * 49152);
  k_build_wcomb<<<1536, 256, 0, stream>>>(tl_uiou, tl_wiou, WCOMB);
  k_zero_misc<<<512, 256, 0, stream>>>(NEI, DEG, FLAG);
  k_mask_detect<<<128, 256, 0, stream>>>((const unsigned*)ast_mask_raw, FLAG);
  k_mask_convert<<<512, 256, 0, stream>>>(ast_mask_raw, FLAG, MSK);

  // ---- 3 sequence encoders: slots 0 (stmt), 2 (varn), 3 (vart) ----
  const int slot_of[3] = {0, 2, 3};
  for (int e = 0; e < 3; ++e) {
    gemm(seq_emb + (size_t)e * 50000 * 256, seq_tokens + (size_t)e * 32768, 256,
         seq_wih + (size_t)e * 768 * 256, seq_bih + (size_t)e * 768, GI,
         32768, 256, 768, 0);
    k_gru<<<dim3(64, 2), 256, 0, stream>>>(GI, WHHT + (size_t)e * 2 * 49152,
                                           seq_bhh + (size_t)e * 768, OUT, 512, 64);
    k_attn_pool<<<512, 256, 0, stream>>>(OUT, 64 * 256, 256, OUT, 64 * 256, 256,
                                         seq_pw + e * 256, seq_pb + e,
                                         FEATS + slot_of[e] * 256, 1280, 64);
  }

  // ---- ctx encoder (needs stmt slot0): slot 4 ----
  gemm(FEATS, ctx_nei, 1280, ctx_wih, ctx_bih, GI, 4096, 256, 768, 0);
  k_gru<<<dim3(64, 2), 256, 0, stream>>>(GI, WHHT + 6 * 49152, ctx_bhh, OUT, 512, 8);
  k_attn_pool<<<512, 256, 0, stream>>>(OUT, 8 * 256, 256, OUT, 8 * 256, 256,
                                       ctx_pw, ctx_pb, FEATS + 4 * 256, 1280, 8);

  // ---- AST TreeLSTM: slot 1 ----
  k_xn<<<32768, 256, 0, stream>>>(ast_label_tab, ast_tok_tab, ast_label_ids,
                                  ast_tok_ids, XN);
  gemm(XN, nullptr, 256, tl_wf, tl_bf, XF, 32768, 256, 256, 0);
  for (int m = 0; m < 64; ++m) {
    k_tl_gemm<<<224, 256, 0, stream>>>(HARR, XN, ast_children, MSK, WCOMB, tl_uf,
                                       tl_biou, IOU, FGH, m);
    k_tl_combine<<<512, 256, 0, stream>>>(IOU, FGH, XF, ast_children, MSK,
                                          HARR, CARR, m);
  }
  k_attn_pool<<<512, 256, 0, stream>>>(HARR, 256, 512 * 256, HARR, 256, 512 * 256,
                                       ast_pw, ast_pb, FEATS + 1 * 256, 1280, 64);

  // ---- feature-attention biGRU over the 5 slots -> x ----
  gemm(FEATS, nullptr, 256, fa_wih, fa_bih, GIFA, 2560, 256, 768, 0);
  k_gru<<<dim3(64, 2), 256, 0, stream>>>(GIFA, WHHT + 8 * 49152, fa_bhh, OUTFA, 512, 5);
  k_attn_pool<<<512, 256, 0, stream>>>(OUTFA, 5 * 256, 256, FEATS, 1280, 256,
                                       fa_aw, fa_ab, X, 256, 5);

  // ---- graph section ----
  k_edge_deg<<<(E + 255) / 256, 256, 0, stream>>>(edges, DEG, E);
  k_nei<<<E, 256, 0, stream>>>(edges, X, NEI);
  k_xcat<<<512, 256, 0, stream>>>(X, NEI, DEG, XCAT);
  gemm(XCAT, nullptr, 512, comb_w, comb_b, X2, 512, 512, 256, 1);
  gemm(X2, nullptr, 256, g1_w, g1_b, Y, 512, 256, 256, 0);
  k_spmm_self<<<512, 256, 0, stream>>>(Y, DEG, H1);
  k_spmm_edge<<<E, 256, 0, stream>>>(Y, DEG, edges, H1);
  k_relu_inplace<<<512, 256, 0, stream>>>(H1);
  gemm(H1, nullptr, 256, g2_w, g2_b, Y, 512, 256, 256, 0);
  k_spmm_self<<<512, 256, 0, stream>>>(Y, DEG, H2);
  k_spmm_edge<<<E, 256, 0, stream>>>(Y, DEG, edges, H2);
  k_relu_inplace<<<512, 256, 0, stream>>>(H2);
  k_final<<<1, 256, 0, stream>>>(H2, cls_w1, cls_b1, cls_w2, cls_b2, outp);
}

// Round 2
// 4348.004 us; speedup vs baseline: 2.0310x; 2.0310x over previous
//
#include <hip/hip_runtime.h>
#include <cmath>

// ---------------------------------------------------------------------------
// Model dims: H=256 HID=128 V=50000 LV=200 N=512 L=64 M=64 C=4 T=8 K=8
// ---------------------------------------------------------------------------

__device__ __forceinline__ float sigf(float x) { return 1.f / (1.f + expf(-x)); }

// ---------------------------------------------------------------------------
// W_comb[j][k] : k<256 -> uiou[j][k] ; k>=256 -> wiou[j][k-256]   (768x512)
// ---------------------------------------------------------------------------
__global__ __launch_bounds__(256) void k_build_wcomb(const float* __restrict__ uiou,
                                                     const float* __restrict__ wiou,
                                                     float* __restrict__ wc) {
  int i = blockIdx.x * 256 + threadIdx.x;  // < 768*512
  if (i >= 768 * 512) return;
  int j = i >> 9;
  int k = i & 511;
  wc[i] = (k < 256) ? uiou[j * 256 + k] : wiou[j * 256 + (k - 256)];
}

__global__ __launch_bounds__(256) void k_zero_misc(float* __restrict__ nei_sum,
                                                   int* __restrict__ deg,
                                                   int* __restrict__ flag) {
  int i = blockIdx.x * 256 + threadIdx.x;
  if (i < 512 * 256) nei_sum[i] = 0.f;
  if (i < 512) deg[i] = 0;
  if (i == 0) *flag = 0;
}

// bool-mask dtype detector (int32 vs byte-packed)
__global__ __launch_bounds__(256) void k_mask_detect(const unsigned* __restrict__ raw,
                                                     int* __restrict__ flag) {
  int i = blockIdx.x * 256 + threadIdx.x;
  if (i < 32768) {
    if (raw[i] > 1u) atomicOr(flag, 1);
  }
}

__global__ __launch_bounds__(256) void k_mask_convert(const void* __restrict__ raw,
                                                      const int* __restrict__ flag,
                                                      int* __restrict__ msk) {
  int i = blockIdx.x * 256 + threadIdx.x;  // < 131072
  if (i >= 512 * 64 * 4) return;
  int v;
  if (*flag) v = ((const unsigned char*)raw)[i] != 0;
  else       v = ((const int*)raw)[i] != 0;
  msk[i] = v;
}

// ---------------------------------------------------------------------------
// Generic fp32 GEMM: 128x128 tile, 256 threads, 8x8 micro, K chunked by 8.
// ---------------------------------------------------------------------------
__global__ __launch_bounds__(256) void k_gemm128(const float* __restrict__ A,
                                                 const int* __restrict__ ridx,
                                                 int rstride,
                                                 const float* __restrict__ W,
                                                 const float* __restrict__ bias,
                                                 float* __restrict__ C,
                                                 int R, int K, int J, int relu) {
  __shared__ float As[8][132];
  __shared__ float Ws[8][132];
  int njt = J >> 7;
  int rt = blockIdx.x / njt;
  int jt = blockIdx.x % njt;
  int tid = threadIdx.x;
  int tx = tid & 15, ty = tid >> 4;

  int row2 = tid >> 1;
  int kq = (tid & 1) * 4;
  int gr = rt * 128 + row2;
  const float* arow = A + (size_t)(ridx ? ridx[gr] : gr) * rstride;
  const float* wrow = W + (size_t)(jt * 128 + row2) * K;

  float acc[8][8];
#pragma unroll
  for (int i = 0; i < 8; ++i)
#pragma unroll
    for (int j = 0; j < 8; ++j) acc[i][j] = 0.f;

  for (int k0 = 0; k0 < K; k0 += 8) {
    float4 av = *(const float4*)(arow + k0 + kq);
    float4 wv = *(const float4*)(wrow + k0 + kq);
    __syncthreads();
    As[kq + 0][row2] = av.x; As[kq + 1][row2] = av.y;
    As[kq + 2][row2] = av.z; As[kq + 3][row2] = av.w;
    Ws[kq + 0][row2] = wv.x; Ws[kq + 1][row2] = wv.y;
    Ws[kq + 2][row2] = wv.z; Ws[kq + 3][row2] = wv.w;
    __syncthreads();
#pragma unroll
    for (int kk = 0; kk < 8; ++kk) {
      float a[8], b[8];
      *(float4*)&a[0] = *(const float4*)&As[kk][ty * 8];
      *(float4*)&a[4] = *(const float4*)&As[kk][ty * 8 + 4];
      *(float4*)&b[0] = *(const float4*)&Ws[kk][tx * 8];
      *(float4*)&b[4] = *(const float4*)&Ws[kk][tx * 8 + 4];
#pragma unroll
      for (int i = 0; i < 8; ++i)
#pragma unroll
        for (int j = 0; j < 8; ++j) acc[i][j] += a[i] * b[j];
    }
  }

  int colbase = jt * 128 + tx * 8;
  float bb[8];
#pragma unroll
  for (int j = 0; j < 8; ++j) bb[j] = bias ? bias[colbase + j] : 0.f;
#pragma unroll
  for (int i = 0; i < 8; ++i) {
    int row = rt * 128 + ty * 8 + i;
    float* crow = C + (size_t)row * J + colbase;
#pragma unroll
    for (int j = 0; j < 8; ++j) {
      float v = acc[i][j] + bb[j];
      if (relu) v = fmaxf(v, 0.f);
      crow[j] = v;
    }
  }
}

// ---------------------------------------------------------------------------
// GRU recurrence, weight-stationary in registers.
//   Block: 384 threads, one direction, 2 samples (n0, n0+1).
//   Thread (rowgrp=tid>>3, ks=tid&7): holds whh rows [rowgrp*8 .. +7],
//   k chunk [ks*16 .. +15] in 128 VGPRs (loaded once).
//   Per step: dot from h in LDS, partials to padded LDS, threads 0..255
//   reduce + apply gates.
//   whh layout: original [2][384][128] (no transpose needed).
// ---------------------------------------------------------------------------
__global__ __launch_bounds__(384, 3) void k_gru2(const float* __restrict__ gi,
                                                 const float* __restrict__ whh,
                                                 const float* __restrict__ bhh,
                                                 float* __restrict__ out,
                                                 int L) {
  __shared__ float hs[2][128];
  __shared__ float parts[2][8][388];  // padded: stride 388 -> conflict-free
  int tid = threadIdx.x;
  int d = blockIdx.y;
  int n0 = blockIdx.x * 2;
  int rowgrp = tid >> 3, ks = tid & 7;
  int j0 = rowgrp * 8;
  int kb = ks * 16;
  const float* wbase = whh + (size_t)d * 384 * 128;

  float4 w4[8][4];
#pragma unroll
  for (int r = 0; r < 8; ++r) {
    const float* wr = wbase + (size_t)(j0 + r) * 128 + kb;
#pragma unroll
    for (int q = 0; q < 4; ++q) w4[r][q] = ((const float4*)wr)[q];
  }

  if (tid < 256) hs[tid >> 7][tid & 127] = 0.f;
  __syncthreads();

  int t = d ? (L - 1) : 0;
  int dt = d ? -1 : 1;
  const float* bh = bhh + d * 384;

  for (int step = 0; step < L; ++step, t += dt) {
    float acc[2][8];
#pragma unroll
    for (int s = 0; s < 2; ++s)
#pragma unroll
      for (int r = 0; r < 8; ++r) acc[s][r] = 0.f;
#pragma unroll
    for (int s = 0; s < 2; ++s) {
#pragma unroll
      for (int q = 0; q < 4; ++q) {
        float4 hv = *(const float4*)&hs[s][kb + q * 4];
#pragma unroll
        for (int r = 0; r < 8; ++r) {
          acc[s][r] += w4[r][q].x * hv.x + w4[r][q].y * hv.y +
                       w4[r][q].z * hv.z + w4[r][q].w * hv.w;
        }
      }
    }
#pragma unroll
    for (int s = 0; s < 2; ++s) {
      *(float4*)&parts[s][ks][j0] =
          make_float4(acc[s][0], acc[s][1], acc[s][2], acc[s][3]);
      *(float4*)&parts[s][ks][j0 + 4] =
          make_float4(acc[s][4], acc[s][5], acc[s][6], acc[s][7]);
    }
    __syncthreads();
    if (tid < 256) {
      int s = tid >> 7, j = tid & 127;
      int n = n0 + s;
      float gr_ = 0.f, gz_ = 0.f, gn_ = 0.f;
#pragma unroll
      for (int k = 0; k < 8; ++k) {
        gr_ += parts[s][k][j];
        gz_ += parts[s][k][128 + j];
        gn_ += parts[s][k][256 + j];
      }
      const float* g = gi + (size_t)(n * L + t) * 768 + d * 384;
      float hr = gr_ + bh[j];
      float hz = gz_ + bh[128 + j];
      float hn = gn_ + bh[256 + j];
      float r = sigf(g[j] + hr);
      float z = sigf(g[128 + j] + hz);
      float nn = tanhf(g[256 + j] + r * hn);
      float hold = hs[s][j];
      float hnew = (1.f - z) * nn + z * hold;
      hs[s][j] = hnew;
      out[(size_t)(n * L + t) * 256 + d * 128 + j] = hnew;
    }
    __syncthreads();
  }
}

// ---------------------------------------------------------------------------
// Attention pool (one block per n)
// ---------------------------------------------------------------------------
__global__ __launch_bounds__(256) void k_attn_pool(const float* __restrict__ score_src,
                                                   int s_ns, int s_ls,
                                                   const float* __restrict__ val_src,
                                                   int v_ns, int v_ls,
                                                   const float* __restrict__ w,
                                                   const float* __restrict__ bptr,
                                                   float* __restrict__ dst,
                                                   int dst_stride, int L) {
  __shared__ float wts[64];
  int n = blockIdx.x;
  int tid = threadIdx.x;
  if (tid < 64) {
    float a = -INFINITY;
    if (tid < L) {
      const float* row = score_src + (size_t)n * s_ns + (size_t)tid * s_ls;
      float s = bptr[0];
      for (int h = 0; h < 256; h += 4) {
        float4 v = *(const float4*)(row + h);
        float4 wv = *(const float4*)(w + h);
        s += v.x * wv.x + v.y * wv.y + v.z * wv.z + v.w * wv.w;
      }
      a = s;
    }
    float mx = a;
#pragma unroll
    for (int off = 32; off; off >>= 1) mx = fmaxf(mx, __shfl_xor(mx, off));
    float e = (tid < L) ? expf(a - mx) : 0.f;
    float ss = e;
#pragma unroll
    for (int off = 32; off; off >>= 1) ss += __shfl_xor(ss, off);
    if (tid < L) wts[tid] = e / ss;
  }
  __syncthreads();
  float acc = 0.f;
  for (int l = 0; l < L; ++l)
    acc += wts[l] * val_src[(size_t)n * v_ns + (size_t)l * v_ls + tid];
  dst[(size_t)n * dst_stride + tid] = acc;
}

// ---------------------------------------------------------------------------
// xn[n][m][h] = 0.5*label_tab[lbl][h] + (1/16)*sum_t tok_tab[id][h]
// ---------------------------------------------------------------------------
__global__ __launch_bounds__(256) void k_xn(const float* __restrict__ label_tab,
                                            const float* __restrict__ tok_tab,
                                            const int* __restrict__ lbl_ids,
                                            const int* __restrict__ tok_ids,
                                            float* __restrict__ xn) {
  int nm = blockIdx.x;
  int h = threadIdx.x;
  const int* tids = tok_ids + (size_t)nm * 8;
  float s = 0.f;
#pragma unroll
  for (int t = 0; t < 8; ++t) s += tok_tab[(size_t)tids[t] * 256 + h];
  xn[(size_t)nm * 256 + h] = 0.5f * label_tab[(size_t)lbl_ids[nm] * 256 + h] + 0.0625f * s;
}

// ---------------------------------------------------------------------------
// TreeLSTM: init ACAT/CHH for step 0 (mask at m=0 is all-false).
//   ACAT[n] = [hsum(=0) | xn[n][0]], CHH = 0
// ---------------------------------------------------------------------------
__global__ __launch_bounds__(256) void k_tl_init(const float* __restrict__ xn,
                                                 float* __restrict__ ACAT,
                                                 float* __restrict__ CHH) {
  int n = blockIdx.x, h = threadIdx.x;
  ACAT[(size_t)n * 512 + h] = 0.f;
  ACAT[(size_t)n * 512 + 256 + h] = xn[(size_t)n * 64 * 256 + h];
#pragma unroll
  for (int c = 0; c < 4; ++c) CHH[((size_t)(n * 4 + c)) * 256 + h] = 0.f;
}

// ---------------------------------------------------------------------------
// TreeLSTM step GEMMs, dense inputs (gather already done by combine).
//   b<96 : iou tile (rt=b/12, jt=b%12): iou = ACAT @ wcomb.T + biou
//   b>=96: fg tile: fgh = CHH @ uf.T
//   64x64 tile, 256 threads, 4x4 micro, K chunked by 16.
// ---------------------------------------------------------------------------
__global__ __launch_bounds__(256) void k_tl_gemm2(const float* __restrict__ ACAT,
                                                  const float* __restrict__ CHH,
                                                  const float* __restrict__ wcomb,
                                                  const float* __restrict__ uf,
                                                  const float* __restrict__ biou,
                                                  float* __restrict__ iou,
                                                  float* __restrict__ fgh) {
  __shared__ float As[16][68];
  __shared__ float Ws[16][68];
  int b = blockIdx.x;
  int tid = threadIdx.x;
  bool isIou = b < 96;
  int rt, jt, K, Astride;
  const float* W;
  const float* A;
  if (isIou) { rt = b / 12; jt = b % 12; K = 512; W = wcomb; A = ACAT; Astride = 512; }
  else { int bb = b - 96; rt = bb / 4; jt = bb % 4; K = 256; W = uf; A = CHH; Astride = 256; }

  int tx = tid & 15, ty = tid >> 4;
  int row = tid >> 2;
  int kq = (tid & 3) * 4;

  float acc[4][4];
#pragma unroll
  for (int i = 0; i < 4; ++i)
#pragma unroll
    for (int j = 0; j < 4; ++j) acc[i][j] = 0.f;

  const float* arow = A + (size_t)(rt * 64 + row) * Astride;
  const float* wrow = W + (size_t)(jt * 64 + row) * K;

  for (int k0 = 0; k0 < K; k0 += 16) {
    float4 av = *(const float4*)(arow + k0 + kq);
    float4 wv = *(const float4*)(wrow + k0 + kq);
    __syncthreads();
    As[kq + 0][row] = av.x; As[kq + 1][row] = av.y;
    As[kq + 2][row] = av.z; As[kq + 3][row] = av.w;
    Ws[kq + 0][row] = wv.x; Ws[kq + 1][row] = wv.y;
    Ws[kq + 2][row] = wv.z; Ws[kq + 3][row] = wv.w;
    __syncthreads();
#pragma unroll
    for (int kk = 0; kk < 16; ++kk) {
      float a[4], bv[4];
      *(float4*)&a[0] = *(const float4*)&As[kk][ty * 4];
      *(float4*)&bv[0] = *(const float4*)&Ws[kk][tx * 4];
#pragma unroll
      for (int i = 0; i < 4; ++i)
#pragma unroll
        for (int j = 0; j < 4; ++j) acc[i][j] += a[i] * bv[j];
    }
  }

  int colbase = jt * 64 + tx * 4;
  if (isIou) {
    float bb[4];
#pragma unroll
    for (int j = 0; j < 4; ++j) bb[j] = biou[colbase + j];
#pragma unroll
    for (int i = 0; i < 4; ++i) {
      int n = rt * 64 + ty * 4 + i;
      float* crow = iou + (size_t)n * 768 + colbase;
#pragma unroll
      for (int j = 0; j < 4; ++j) crow[j] = acc[i][j] + bb[j];
    }
  } else {
#pragma unroll
    for (int i = 0; i < 4; ++i) {
      int rr = rt * 64 + ty * 4 + i;
      float* crow = fgh + (size_t)rr * 256 + colbase;
#pragma unroll
      for (int j = 0; j < 4; ++j) crow[j] = acc[i][j];
    }
  }
}

// ---------------------------------------------------------------------------
// TreeLSTM combine for step m + gather/prep of ACAT/CHH for step m+1.
// ---------------------------------------------------------------------------
__global__ __launch_bounds__(256) void k_tl_combine2(const float* __restrict__ iou,
                                                     const float* __restrict__ fgh,
                                                     const float* __restrict__ xf,
                                                     const float* __restrict__ xn,
                                                     const int* __restrict__ ch,
                                                     const int* __restrict__ msk,
                                                     float* __restrict__ h_arr,
                                                     float* __restrict__ c_arr,
                                                     float* __restrict__ ACAT,
                                                     float* __restrict__ CHH,
                                                     int m) {
  int n = blockIdx.x, h = threadIdx.x;
  float iv = sigf(iou[(size_t)n * 768 + h]);
  float ov = sigf(iou[(size_t)n * 768 + 256 + h]);
  float uv = tanhf(iou[(size_t)n * 768 + 512 + h]);
  const int* chp = ch + ((size_t)(n * 64 + m)) * 4;
  const int* mkp = msk + ((size_t)(n * 64 + m)) * 4;
  float xfv = xf[((size_t)(n * 64 + m)) * 256 + h];
  float cs = 0.f;
#pragma unroll
  for (int c = 0; c < 4; ++c) {
    if (mkp[c]) {
      float cc = c_arr[((size_t)chp[c] * 512 + n) * 256 + h];
      float fg = sigf(xfv + fgh[((size_t)(n * 4 + c)) * 256 + h]);
      cs += fg * cc;
    }
  }
  float cn = iv * uv + cs;
  float hn = ov * tanhf(cn);
  h_arr[((size_t)m * 512 + n) * 256 + h] = hn;
  c_arr[((size_t)m * 512 + n) * 256 + h] = cn;

  // prep step m+1
  int mm = m + 1;
  if (mm < 64) {
    const int* chp2 = ch + ((size_t)(n * 64 + mm)) * 4;
    const int* mkp2 = msk + ((size_t)(n * 64 + mm)) * 4;
    float hsum = 0.f;
#pragma unroll
    for (int c = 0; c < 4; ++c) {
      float hv = 0.f;
      if (mkp2[c]) {
        int cc = chp2[c];
        hv = (cc == m) ? hn : h_arr[((size_t)cc * 512 + n) * 256 + h];
      }
      CHH[((size_t)(n * 4 + c)) * 256 + h] = hv;
      hsum += hv;
    }
    ACAT[(size_t)n * 512 + h] = hsum;
    ACAT[(size_t)n * 512 + 256 + h] = xn[((size_t)(n * 64 + mm)) * 256 + h];
  }
}

// ---------------------------------------------------------------------------
// Graph kernels
// ---------------------------------------------------------------------------
__global__ __launch_bounds__(256) void k_edge_deg(const int* __restrict__ edges,
                                                  int* __restrict__ deg, int E) {
  int i = blockIdx.x * 256 + threadIdx.x;
  if (i < E) {
    atomicAdd(&deg[edges[2 * i]], 1);
    atomicAdd(&deg[edges[2 * i + 1]], 1);
  }
}

__global__ __launch_bounds__(256) void k_nei(const int* __restrict__ edges,
                                             const float* __restrict__ x,
                                             float* __restrict__ nei_sum) {
  int e = blockIdx.x, h = threadIdx.x;
  int a = edges[2 * e], b = edges[2 * e + 1];
  atomicAdd(&nei_sum[(size_t)a * 256 + h], x[(size_t)b * 256 + h]);
  atomicAdd(&nei_sum[(size_t)b * 256 + h], x[(size_t)a * 256 + h]);
}

__global__ __launch_bounds__(256) void k_xcat(const float* __restrict__ x,
                                              const float* __restrict__ nei_sum,
                                              const int* __restrict__ deg,
                                              float* __restrict__ xcat) {
  int n = blockIdx.x, h = threadIdx.x;
  xcat[(size_t)n * 512 + h] = x[(size_t)n * 256 + h];
  float d = fmaxf((float)deg[n], 1.f);
  xcat[(size_t)n * 512 + 256 + h] = nei_sum[(size_t)n * 256 + h] / d;
}

__global__ __launch_bounds__(256) void k_spmm_self(const float* __restrict__ y,
                                                   const int* __restrict__ deg,
                                                   float* __restrict__ ob) {
  int n = blockIdx.x, h = threadIdx.x;
  float dis2 = 1.f / (float)(deg[n] + 1);
  ob[(size_t)n * 256 + h] = dis2 * y[(size_t)n * 256 + h];
}

__global__ __launch_bounds__(256) void k_spmm_edge(const float* __restrict__ y,
                                                   const int* __restrict__ deg,
                                                   const int* __restrict__ edges,
                                                   float* __restrict__ ob) {
  int e = blockIdx.x, h = threadIdx.x;
  int a = edges[2 * e], b = edges[2 * e + 1];
  float w = (1.f / sqrtf((float)(deg[a] + 1))) * (1.f / sqrtf((float)(deg[b] + 1)));
  atomicAdd(&ob[(size_t)a * 256 + h], w * y[(size_t)b * 256 + h]);
  atomicAdd(&ob[(size_t)b * 256 + h], w * y[(size_t)a * 256 + h]);
}

__global__ __launch_bounds__(256) void k_relu_inplace(float* __restrict__ p) {
  int i = blockIdx.x * 256 + threadIdx.x;
  p[i] = fmaxf(p[i], 0.f);
}

__global__ __launch_bounds__(256) void k_final(const float* __restrict__ h2,
                                               const float* __restrict__ w1,
                                               const float* __restrict__ b1,
                                               const float* __restrict__ w2,
                                               const float* __restrict__ b2,
                                               float* __restrict__ outp) {
  __shared__ float gv[512];
  __shared__ float zz[256];
  int tid = threadIdx.x;
  float mn = 0.f, mx = -INFINITY;
  for (int n = 0; n < 512; ++n) {
    float v = h2[(size_t)n * 256 + tid];
    mn += v;
    mx = fmaxf(mx, v);
  }
  gv[tid] = mn / 512.f;
  gv[256 + tid] = mx;
  __syncthreads();
  float acc = b1[tid];
  for (int k = 0; k < 512; ++k) acc += gv[k] * w1[(size_t)tid * 512 + k];
  zz[tid] = fmaxf(acc, 0.f) * w2[tid];
  __syncthreads();
  for (int s = 128; s; s >>= 1) {
    if (tid < s) zz[tid] += zz[tid + s];
    __syncthreads();
  }
  if (tid == 0) outp[0] = zz[0] + b2[0];
}

// ---------------------------------------------------------------------------
// Host launch
// ---------------------------------------------------------------------------
extern "C" void kernel_launch(void* const* d_in, const int* in_sizes, int n_in,
                              void* d_out, int out_size, void* d_ws, size_t ws_size,
                              hipStream_t stream) {
  const int* seq_tokens    = (const int*)d_in[0];
  const int* ast_children  = (const int*)d_in[1];
  const void* ast_mask_raw = (const void*)d_in[2];
  const int* ast_label_ids = (const int*)d_in[3];
  const int* ast_tok_ids   = (const int*)d_in[4];
  const int* ctx_nei       = (const int*)d_in[5];
  const int* edges         = (const int*)d_in[6];
  const float* seq_emb  = (const float*)d_in[7];
  const float* seq_wih  = (const float*)d_in[8];
  const float* seq_whh  = (const float*)d_in[9];
  const float* seq_bih  = (const float*)d_in[10];
  const float* seq_bhh  = (const float*)d_in[11];
  const float* seq_pw   = (const float*)d_in[12];
  const float* seq_pb   = (const float*)d_in[13];
  const float* ctx_wih  = (const float*)d_in[14];
  const float* ctx_whh  = (const float*)d_in[15];
  const float* ctx_bih  = (const float*)d_in[16];
  const float* ctx_bhh  = (const float*)d_in[17];
  const float* ctx_pw   = (const float*)d_in[18];
  const float* ctx_pb   = (const float*)d_in[19];
  const float* ast_label_tab = (const float*)d_in[20];
  const float* ast_tok_tab   = (const float*)d_in[21];
  const float* ast_pw   = (const float*)d_in[22];
  const float* ast_pb   = (const float*)d_in[23];
  const float* tl_wiou  = (const float*)d_in[24];
  const float* tl_biou  = (const float*)d_in[25];
  const float* tl_uiou  = (const float*)d_in[26];
  const float* tl_wf    = (const float*)d_in[27];
  const float* tl_bf    = (const float*)d_in[28];
  const float* tl_uf    = (const float*)d_in[29];
  const float* fa_wih   = (const float*)d_in[30];
  const float* fa_whh   = (const float*)d_in[31];
  const float* fa_bih   = (const float*)d_in[32];
  const float* fa_bhh   = (const float*)d_in[33];
  const float* fa_aw    = (const float*)d_in[34];
  const float* fa_ab    = (const float*)d_in[35];
  const float* comb_w   = (const float*)d_in[36];
  const float* comb_b   = (const float*)d_in[37];
  const float* g1_w     = (const float*)d_in[38];
  const float* g1_b     = (const float*)d_in[39];
  const float* g2_w     = (const float*)d_in[40];
  const float* g2_b     = (const float*)d_in[41];
  const float* cls_w1   = (const float*)d_in[42];
  const float* cls_b1   = (const float*)d_in[43];
  const float* cls_w2   = (const float*)d_in[44];
  const float* cls_b2   = (const float*)d_in[45];
  float* outp = (float*)d_out;
  float* ws = (float*)d_ws;
  int E = in_sizes[6] / 2;

  // ----- workspace layout (floats) -----
  size_t off = 0;
  auto take = [&](size_t n) { size_t o = off; off += n; return o; };
  const size_t F_FEATS = take(512 * 5 * 256);
  const size_t F_X     = take(512 * 256);
  const size_t F_X2    = take(512 * 256);
  const size_t F_Y     = take(512 * 256);
  const size_t F_H1    = take(512 * 256);
  const size_t F_H2    = take(512 * 256);
  const size_t F_XCAT  = take(512 * 512);
  const size_t F_NEI   = take(512 * 256);
  const size_t F_DEG   = take(512);
  const size_t F_FLAG  = take(16);
  const size_t F_MSK   = take(512 * 64 * 4);
  const size_t F_WCOMB = take(768 * 512);
  const size_t F_IOU   = take(512 * 768);
  const size_t F_FGH   = take(2048 * 256);
  const size_t F_ACAT  = take(512 * 512);
  const size_t F_CHH   = take(2048 * 256);
  const size_t F_REGION = take(33554432);
  (void)ws_size;

  float* FEATS = ws + F_FEATS;
  float* X     = ws + F_X;
  float* X2    = ws + F_X2;
  float* Y     = ws + F_Y;
  float* H1    = ws + F_H1;
  float* H2    = ws + F_H2;
  float* XCAT  = ws + F_XCAT;
  float* NEI   = ws + F_NEI;
  int*   DEG   = (int*)(ws + F_DEG);
  int*   FLAG  = (int*)(ws + F_FLAG);
  int*   MSK   = (int*)(ws + F_MSK);
  float* WCOMB = ws + F_WCOMB;
  float* IOU   = ws + F_IOU;
  float* FGH   = ws + F_FGH;
  float* ACAT  = ws + F_ACAT;
  float* CHH   = ws + F_CHH;
  float* GI    = ws + F_REGION;                 // 25165824 (enc/ctx gi)
  float* OUT   = ws + F_REGION + 25165824;      // 8388608  (enc/ctx gru out)
  float* XN    = ws + F_REGION;                 // 8388608  (ast phase)
  float* XF    = XN + 8388608;
  float* HARR  = XF + 8388608;
  float* CARR  = HARR + 8388608;
  float* GIFA  = ws + F_REGION;                 // fa phase
  float* OUTFA = GIFA + 1966080;

  auto gemm = [&](const float* A, const int* ridx, int rstride, const float* W,
                  const float* bias, float* C, int R, int K, int J, int relu) {
    dim3 g((R / 128) * (J / 128));
    k_gemm128<<<g, 256, 0, stream>>>(A, ridx, rstride, W, bias, C, R, K, J, relu);
  };

  // ---- prep ----
  k_build_wcomb<<<1536, 256, 0, stream>>>(tl_uiou, tl_wiou, WCOMB);
  k_zero_misc<<<512, 256, 0, stream>>>(NEI, DEG, FLAG);
  k_mask_detect<<<128, 256, 0, stream>>>((const unsigned*)ast_mask_raw, FLAG);
  k_mask_convert<<<512, 256, 0, stream>>>(ast_mask_raw, FLAG, MSK);

  // ---- 3 sequence encoders: slots 0 (stmt), 2 (varn), 3 (vart) ----
  const int slot_of[3] = {0, 2, 3};
  for (int e = 0; e < 3; ++e) {
    gemm(seq_emb + (size_t)e * 50000 * 256, seq_tokens + (size_t)e * 32768, 256,
         seq_wih + (size_t)e * 768 * 256, seq_bih + (size_t)e * 768, GI,
         32768, 256, 768, 0);
    k_gru2<<<dim3(256, 2), 384, 0, stream>>>(GI, seq_whh + (size_t)e * 2 * 384 * 128,
                                             seq_bhh + (size_t)e * 768, OUT, 64);
    k_attn_pool<<<512, 256, 0, stream>>>(OUT, 64 * 256, 256, OUT, 64 * 256, 256,
                                         seq_pw + e * 256, seq_pb + e,
                                         FEATS + slot_of[e] * 256, 1280, 64);
  }

  // ---- ctx encoder (needs stmt slot0): slot 4 ----
  gemm(FEATS, ctx_nei, 1280, ctx_wih, ctx_bih, GI, 4096, 256, 768, 0);
  k_gru2<<<dim3(256, 2), 384, 0, stream>>>(GI, ctx_whh, ctx_bhh, OUT, 8);
  k_attn_pool<<<512, 256, 0, stream>>>(OUT, 8 * 256, 256, OUT, 8 * 256, 256,
                                       ctx_pw, ctx_pb, FEATS + 4 * 256, 1280, 8);

  // ---- AST TreeLSTM: slot 1 ----
  k_xn<<<32768, 256, 0, stream>>>(ast_label_tab, ast_tok_tab, ast_label_ids,
                                  ast_tok_ids, XN);
  gemm(XN, nullptr, 256, tl_wf, tl_bf, XF, 32768, 256, 256, 0);
  k_tl_init<<<512, 256, 0, stream>>>(XN, ACAT, CHH);
  for (int m = 0; m < 64; ++m) {
    k_tl_gemm2<<<224, 256, 0, stream>>>(ACAT, CHH, WCOMB, tl_uf, tl_biou, IOU, FGH);
    k_tl_combine2<<<512, 256, 0, stream>>>(IOU, FGH, XF, XN, ast_children, MSK,
                                           HARR, CARR, ACAT, CHH, m);
  }
  k_attn_pool<<<512, 256, 0, stream>>>(HARR, 256, 512 * 256, HARR, 256, 512 * 256,
                                       ast_pw, ast_pb, FEATS + 1 * 256, 1280, 64);

  // ---- feature-attention biGRU over the 5 slots -> x ----
  gemm(FEATS, nullptr, 256, fa_wih, fa_bih, GIFA, 2560, 256, 768, 0);
  k_gru2<<<dim3(256, 2), 384, 0, stream>>>(GIFA, fa_whh, fa_bhh, OUTFA, 5);
  k_attn_pool<<<512, 256, 0, stream>>>(OUTFA, 5 * 256, 256, FEATS, 1280, 256,
                                       fa_aw, fa_ab, X, 256, 5);

  // ---- graph section ----
  k_edge_deg<<<(E + 255) / 256, 256, 0, stream>>>(edges, DEG, E);
  k_nei<<<E, 256, 0, stream>>>(edges, X, NEI);
  k_xcat<<<512, 256, 0, stream>>>(X, NEI, DEG, XCAT);
  gemm(XCAT, nullptr, 512, comb_w, comb_b, X2, 512, 512, 256, 1);
  gemm(X2, nullptr, 256, g1_w, g1_b, Y, 512, 256, 256, 0);
  k_spmm_self<<<512, 256, 0, stream>>>(Y, DEG, H1);
  k_spmm_edge<<<E, 256, 0, stream>>>(Y, DEG, edges, H1);
  k_relu_inplace<<<512, 256, 0, stream>>>(H1);
  gemm(H1, nullptr, 256, g2_w, g2_b, Y, 512, 256, 256, 0);
  k_spmm_self<<<512, 256, 0, stream>>>(Y, DEG, H2);
  k_spmm_edge<<<E, 256, 0, stream>>>(Y, DEG, edges, H2);
  k_relu_inplace<<<512, 256, 0, stream>>>(H2);
  k_final<<<1, 256, 0, stream>>>(H2, cls_w1, cls_b1, cls_w2, cls_b2, outp);
}

// Round 3
// 3858.457 us; speedup vs baseline: 2.2886x; 1.1269x over previous
//
#include <hip/hip_runtime.h>
#include <cmath>

// ---------------------------------------------------------------------------
// Model dims: H=256 HID=128 V=50000 LV=200 N=512 L=64 M=64 C=4 T=8 K=8
// ---------------------------------------------------------------------------

__device__ __forceinline__ float sigf(float x) { return 1.f / (1.f + expf(-x)); }

// ---------------------------------------------------------------------------
// W_comb[j][k] : k<256 -> uiou[j][k] ; k>=256 -> wiou[j][k-256]   (768x512)
// ---------------------------------------------------------------------------
__global__ __launch_bounds__(256) void k_build_wcomb(const float* __restrict__ uiou,
                                                     const float* __restrict__ wiou,
                                                     float* __restrict__ wc) {
  int i = blockIdx.x * 256 + threadIdx.x;  // < 768*512
  if (i >= 768 * 512) return;
  int j = i >> 9;
  int k = i & 511;
  wc[i] = (k < 256) ? uiou[j * 256 + k] : wiou[j * 256 + (k - 256)];
}

__global__ __launch_bounds__(256) void k_zero_misc(float* __restrict__ nei_sum,
                                                   int* __restrict__ deg,
                                                   int* __restrict__ flag) {
  int i = blockIdx.x * 256 + threadIdx.x;
  if (i < 512 * 256) nei_sum[i] = 0.f;
  if (i < 512) deg[i] = 0;
  if (i == 0) *flag = 0;
}

// bool-mask dtype detector (int32 vs byte-packed)
__global__ __launch_bounds__(256) void k_mask_detect(const unsigned* __restrict__ raw,
                                                     int* __restrict__ flag) {
  int i = blockIdx.x * 256 + threadIdx.x;
  if (i < 32768) {
    if (raw[i] > 1u) atomicOr(flag, 1);
  }
}

__global__ __launch_bounds__(256) void k_mask_convert(const void* __restrict__ raw,
                                                      const int* __restrict__ flag,
                                                      int* __restrict__ msk) {
  int i = blockIdx.x * 256 + threadIdx.x;  // < 131072
  if (i >= 512 * 64 * 4) return;
  int v;
  if (*flag) v = ((const unsigned char*)raw)[i] != 0;
  else       v = ((const int*)raw)[i] != 0;
  msk[i] = v;
}

// ---------------------------------------------------------------------------
// Generic fp32 GEMM: 128x128 tile, 256 threads, 8x8 micro, K chunked by 8.
// ---------------------------------------------------------------------------
__global__ __launch_bounds__(256) void k_gemm128(const float* __restrict__ A,
                                                 const int* __restrict__ ridx,
                                                 int rstride,
                                                 const float* __restrict__ W,
                                                 const float* __restrict__ bias,
                                                 float* __restrict__ C,
                                                 int R, int K, int J, int relu) {
  __shared__ float As[8][132];
  __shared__ float Ws[8][132];
  int njt = J >> 7;
  int rt = blockIdx.x / njt;
  int jt = blockIdx.x % njt;
  int tid = threadIdx.x;
  int tx = tid & 15, ty = tid >> 4;

  int row2 = tid >> 1;
  int kq = (tid & 1) * 4;
  int gr = rt * 128 + row2;
  const float* arow = A + (size_t)(ridx ? ridx[gr] : gr) * rstride;
  const float* wrow = W + (size_t)(jt * 128 + row2) * K;

  float acc[8][8];
#pragma unroll
  for (int i = 0; i < 8; ++i)
#pragma unroll
    for (int j = 0; j < 8; ++j) acc[i][j] = 0.f;

  for (int k0 = 0; k0 < K; k0 += 8) {
    float4 av = *(const float4*)(arow + k0 + kq);
    float4 wv = *(const float4*)(wrow + k0 + kq);
    __syncthreads();
    As[kq + 0][row2] = av.x; As[kq + 1][row2] = av.y;
    As[kq + 2][row2] = av.z; As[kq + 3][row2] = av.w;
    Ws[kq + 0][row2] = wv.x; Ws[kq + 1][row2] = wv.y;
    Ws[kq + 2][row2] = wv.z; Ws[kq + 3][row2] = wv.w;
    __syncthreads();
#pragma unroll
    for (int kk = 0; kk < 8; ++kk) {
      float a[8], b[8];
      *(float4*)&a[0] = *(const float4*)&As[kk][ty * 8];
      *(float4*)&a[4] = *(const float4*)&As[kk][ty * 8 + 4];
      *(float4*)&b[0] = *(const float4*)&Ws[kk][tx * 8];
      *(float4*)&b[4] = *(const float4*)&Ws[kk][tx * 8 + 4];
#pragma unroll
      for (int i = 0; i < 8; ++i)
#pragma unroll
        for (int j = 0; j < 8; ++j) acc[i][j] += a[i] * b[j];
    }
  }

  int colbase = jt * 128 + tx * 8;
  float bb[8];
#pragma unroll
  for (int j = 0; j < 8; ++j) bb[j] = bias ? bias[colbase + j] : 0.f;
#pragma unroll
  for (int i = 0; i < 8; ++i) {
    int row = rt * 128 + ty * 8 + i;
    float* crow = C + (size_t)row * J + colbase;
#pragma unroll
    for (int j = 0; j < 8; ++j) {
      float v = acc[i][j] + bb[j];
      if (relu) v = fmaxf(v, 0.f);
      crow[j] = v;
    }
  }
}

// ---------------------------------------------------------------------------
// GRU recurrence v3: weight-stationary, 512 threads, 4 samples, 1 dir.
//   ks = tid>>6 (wave-uniform k-chunk of 16), rg = tid&63.
//   Thread owns gate rows {r*64+rg : r<6} x k-chunk [ks*16, +16): 96 w-regs.
//   Dot-phase LDS reads of h are wave-broadcasts (ks uniform in wave).
//   Partials at parts[s][ks][row] (row = r*64+rg -> lane-consecutive writes).
//   Gate phase: thread (sg=tid>>7, jg=tid&127) owns one (sample, j) unit;
//   gi for the step is prefetched into regs at step top (hides HBM latency).
//   __launch_bounds__(512,2): VGPR cap 256 -> no AGPR demotion of weights.
// ---------------------------------------------------------------------------
__global__ __launch_bounds__(512, 2) void k_gru3(const float* __restrict__ gi,
                                                 const float* __restrict__ whh,
                                                 const float* __restrict__ bhh,
                                                 float* __restrict__ out,
                                                 int L) {
  __shared__ float hs[4][132];
  __shared__ float parts[4][8][388];
  int tid = threadIdx.x;
  int d = blockIdx.y;
  int n0 = blockIdx.x * 4;
  int ks = tid >> 6;        // 0..7, wave-uniform
  int rg = tid & 63;
  int kb = ks * 16;
  const float* wbase = whh + (size_t)d * 384 * 128;

  float4 w4[6][4];
#pragma unroll
  for (int r = 0; r < 6; ++r) {
    const float* wr = wbase + (size_t)(r * 64 + rg) * 128 + kb;
#pragma unroll
    for (int q = 0; q < 4; ++q) w4[r][q] = ((const float4*)wr)[q];
  }

  int sg = tid >> 7, jg = tid & 127;
  const float* bh = bhh + d * 384;
  float br = bh[jg], bz = bh[128 + jg], bn = bh[256 + jg];

  for (int i = tid; i < 4 * 132; i += 512) ((float*)hs)[i] = 0.f;
  __syncthreads();

  int t = d ? (L - 1) : 0;
  int dt = d ? -1 : 1;

  for (int step = 0; step < L; ++step, t += dt) {
    // prefetch gi for the gate phase (independent of h)
    const float* g = gi + (size_t)((n0 + sg) * L + t) * 768 + d * 384;
    float pgr = g[jg], pgz = g[128 + jg], pgn = g[256 + jg];

    float acc[4][6];
#pragma unroll
    for (int s = 0; s < 4; ++s)
#pragma unroll
      for (int r = 0; r < 6; ++r) acc[s][r] = 0.f;
#pragma unroll
    for (int s = 0; s < 4; ++s) {
#pragma unroll
      for (int q = 0; q < 4; ++q) {
        float4 hv = *(const float4*)&hs[s][kb + q * 4];
#pragma unroll
        for (int r = 0; r < 6; ++r) {
          acc[s][r] += w4[r][q].x * hv.x + w4[r][q].y * hv.y +
                       w4[r][q].z * hv.z + w4[r][q].w * hv.w;
        }
      }
    }
#pragma unroll
    for (int s = 0; s < 4; ++s)
#pragma unroll
      for (int r = 0; r < 6; ++r) parts[s][ks][r * 64 + rg] = acc[s][r];
    __syncthreads();
    {
      float sr = 0.f, sz = 0.f, sn = 0.f;
#pragma unroll
      for (int k = 0; k < 8; ++k) {
        sr += parts[sg][k][jg];
        sz += parts[sg][k][128 + jg];
        sn += parts[sg][k][256 + jg];
      }
      float r = sigf(pgr + sr + br);
      float z = sigf(pgz + sz + bz);
      float nn = tanhf(pgn + r * (sn + bn));
      float hold = hs[sg][jg];
      float hnew = (1.f - z) * nn + z * hold;
      hs[sg][jg] = hnew;
      out[(size_t)((n0 + sg) * L + t) * 256 + d * 128 + jg] = hnew;
    }
    __syncthreads();
  }
}

// ---------------------------------------------------------------------------
// Attention pool (one block per n)
// ---------------------------------------------------------------------------
__global__ __launch_bounds__(256) void k_attn_pool(const float* __restrict__ score_src,
                                                   int s_ns, int s_ls,
                                                   const float* __restrict__ val_src,
                                                   int v_ns, int v_ls,
                                                   const float* __restrict__ w,
                                                   const float* __restrict__ bptr,
                                                   float* __restrict__ dst,
                                                   int dst_stride, int L) {
  __shared__ float wts[64];
  int n = blockIdx.x;
  int tid = threadIdx.x;
  if (tid < 64) {
    float a = -INFINITY;
    if (tid < L) {
      const float* row = score_src + (size_t)n * s_ns + (size_t)tid * s_ls;
      float s = bptr[0];
      for (int h = 0; h < 256; h += 4) {
        float4 v = *(const float4*)(row + h);
        float4 wv = *(const float4*)(w + h);
        s += v.x * wv.x + v.y * wv.y + v.z * wv.z + v.w * wv.w;
      }
      a = s;
    }
    float mx = a;
#pragma unroll
    for (int off = 32; off; off >>= 1) mx = fmaxf(mx, __shfl_xor(mx, off));
    float e = (tid < L) ? expf(a - mx) : 0.f;
    float ss = e;
#pragma unroll
    for (int off = 32; off; off >>= 1) ss += __shfl_xor(ss, off);
    if (tid < L) wts[tid] = e / ss;
  }
  __syncthreads();
  float acc = 0.f;
  for (int l = 0; l < L; ++l)
    acc += wts[l] * val_src[(size_t)n * v_ns + (size_t)l * v_ls + tid];
  dst[(size_t)n * dst_stride + tid] = acc;
}

// ---------------------------------------------------------------------------
// xn[n][m][h] = 0.5*label_tab[lbl][h] + (1/16)*sum_t tok_tab[id][h]
// ---------------------------------------------------------------------------
__global__ __launch_bounds__(256) void k_xn(const float* __restrict__ label_tab,
                                            const float* __restrict__ tok_tab,
                                            const int* __restrict__ lbl_ids,
                                            const int* __restrict__ tok_ids,
                                            float* __restrict__ xn) {
  int nm = blockIdx.x;
  int h = threadIdx.x;
  const int* tids = tok_ids + (size_t)nm * 8;
  float s = 0.f;
#pragma unroll
  for (int t = 0; t < 8; ++t) s += tok_tab[(size_t)tids[t] * 256 + h];
  xn[(size_t)nm * 256 + h] = 0.5f * label_tab[(size_t)lbl_ids[nm] * 256 + h] + 0.0625f * s;
}

// ---------------------------------------------------------------------------
// TreeLSTM: init ACAT/CHH for step 0 (mask at m=0 is all-false).
// ---------------------------------------------------------------------------
__global__ __launch_bounds__(256) void k_tl_init(const float* __restrict__ xn,
                                                 float* __restrict__ ACAT,
                                                 float* __restrict__ CHH) {
  int n = blockIdx.x, h = threadIdx.x;
  ACAT[(size_t)n * 512 + h] = 0.f;
  ACAT[(size_t)n * 512 + 256 + h] = xn[(size_t)n * 64 * 256 + h];
#pragma unroll
  for (int c = 0; c < 4; ++c) CHH[((size_t)(n * 4 + c)) * 256 + h] = 0.f;
}

// ---------------------------------------------------------------------------
// TreeLSTM step GEMMs v3: K-split partial GEMMs, 128x128 tiles, 8x8 micro.
//   grid = 320 blocks:
//   b<192 : iou partial: tile=b>>3 (rt=tile/6, jt=tile%6), ks=b&7, K=[ks*64,+64)
//           IOUP[ks][n][j] = sum_k ACAT[n][k]*wcomb[j][k]
//   b>=192: fg partial: bb=b-192, tile=bb>>2 (rt=tile/2, jt=tile%2), ks=bb&3
//           FGP[ks][r][j] = sum_k CHH[r][k]*uf[j][k]
// ---------------------------------------------------------------------------
__global__ __launch_bounds__(256) void k_tl_gemm3(const float* __restrict__ ACAT,
                                                  const float* __restrict__ CHH,
                                                  const float* __restrict__ wcomb,
                                                  const float* __restrict__ uf,
                                                  float* __restrict__ IOUP,
                                                  float* __restrict__ FGP) {
  __shared__ float As[8][132];
  __shared__ float Ws[8][132];
  int b = blockIdx.x;
  int tid = threadIdx.x;
  bool isIou = b < 192;
  int rt, jt, koff, Astride, J;
  const float* A;
  const float* W;
  float* outp;
  if (isIou) {
    int tile = b >> 3, ks = b & 7;
    rt = tile / 6; jt = tile % 6; koff = ks * 64;
    A = ACAT; Astride = 512; W = wcomb; J = 768;
    outp = IOUP + (size_t)ks * 512 * 768;
  } else {
    int bb = b - 192;
    int tile = bb >> 2, ks = bb & 3;
    rt = tile / 2; jt = tile % 2; koff = ks * 64;
    A = CHH; Astride = 256; W = uf; J = 256;
    outp = FGP + (size_t)ks * 2048 * 256;
  }

  int tx = tid & 15, ty = tid >> 4;
  int row2 = tid >> 1;
  int kq = (tid & 1) * 4;
  const float* arow = A + (size_t)(rt * 128 + row2) * Astride + koff;
  const float* wrow = W + (size_t)(jt * 128 + row2) * Astride + koff;

  float acc[8][8];
#pragma unroll
  for (int i = 0; i < 8; ++i)
#pragma unroll
    for (int j = 0; j < 8; ++j) acc[i][j] = 0.f;

  for (int k0 = 0; k0 < 64; k0 += 8) {
    float4 av = *(const float4*)(arow + k0 + kq);
    float4 wv = *(const float4*)(wrow + k0 + kq);
    __syncthreads();
    As[kq + 0][row2] = av.x; As[kq + 1][row2] = av.y;
    As[kq + 2][row2] = av.z; As[kq + 3][row2] = av.w;
    Ws[kq + 0][row2] = wv.x; Ws[kq + 1][row2] = wv.y;
    Ws[kq + 2][row2] = wv.z; Ws[kq + 3][row2] = wv.w;
    __syncthreads();
#pragma unroll
    for (int kk = 0; kk < 8; ++kk) {
      float a[8], bv[8];
      *(float4*)&a[0] = *(const float4*)&As[kk][ty * 8];
      *(float4*)&a[4] = *(const float4*)&As[kk][ty * 8 + 4];
      *(float4*)&bv[0] = *(const float4*)&Ws[kk][tx * 8];
      *(float4*)&bv[4] = *(const float4*)&Ws[kk][tx * 8 + 4];
#pragma unroll
      for (int i = 0; i < 8; ++i)
#pragma unroll
        for (int j = 0; j < 8; ++j) acc[i][j] += a[i] * bv[j];
    }
  }

  int colbase = jt * 128 + tx * 8;
#pragma unroll
  for (int i = 0; i < 8; ++i) {
    int row = rt * 128 + ty * 8 + i;
    float* crow = outp + (size_t)row * J + colbase;
#pragma unroll
    for (int j = 0; j < 8; ++j) crow[j] = acc[i][j];
  }
}

// ---------------------------------------------------------------------------
// TreeLSTM combine v3: reduce partials + gates for step m, prep m+1.
// ---------------------------------------------------------------------------
__global__ __launch_bounds__(256) void k_tl_combine3(const float* __restrict__ IOUP,
                                                     const float* __restrict__ FGP,
                                                     const float* __restrict__ biou,
                                                     const float* __restrict__ xf,
                                                     const float* __restrict__ xn,
                                                     const int* __restrict__ ch,
                                                     const int* __restrict__ msk,
                                                     float* __restrict__ h_arr,
                                                     float* __restrict__ c_arr,
                                                     float* __restrict__ ACAT,
                                                     float* __restrict__ CHH,
                                                     int m) {
  int n = blockIdx.x, h = threadIdx.x;
  float si = 0.f, so = 0.f, su = 0.f;
#pragma unroll
  for (int ks = 0; ks < 8; ++ks) {
    const float* p = IOUP + (size_t)ks * 512 * 768 + (size_t)n * 768 + h;
    si += p[0];
    so += p[256];
    su += p[512];
  }
  float iv = sigf(si + biou[h]);
  float ov = sigf(so + biou[256 + h]);
  float uv = tanhf(su + biou[512 + h]);
  const int* chp = ch + ((size_t)(n * 64 + m)) * 4;
  const int* mkp = msk + ((size_t)(n * 64 + m)) * 4;
  float xfv = xf[((size_t)(n * 64 + m)) * 256 + h];
  float cs = 0.f;
#pragma unroll
  for (int c = 0; c < 4; ++c) {
    if (mkp[c]) {
      float cc = c_arr[((size_t)chp[c] * 512 + n) * 256 + h];
      float fsum = 0.f;
#pragma unroll
      for (int k4 = 0; k4 < 4; ++k4)
        fsum += FGP[(size_t)k4 * 2048 * 256 + ((size_t)(n * 4 + c)) * 256 + h];
      float fg = sigf(xfv + fsum);
      cs += fg * cc;
    }
  }
  float cn = iv * uv + cs;
  float hn = ov * tanhf(cn);
  h_arr[((size_t)m * 512 + n) * 256 + h] = hn;
  c_arr[((size_t)m * 512 + n) * 256 + h] = cn;

  int mm = m + 1;
  if (mm < 64) {
    const int* chp2 = ch + ((size_t)(n * 64 + mm)) * 4;
    const int* mkp2 = msk + ((size_t)(n * 64 + mm)) * 4;
    float hsum = 0.f;
#pragma unroll
    for (int c = 0; c < 4; ++c) {
      float hv = 0.f;
      if (mkp2[c]) {
        int cc = chp2[c];
        hv = (cc == m) ? hn : h_arr[((size_t)cc * 512 + n) * 256 + h];
      }
      CHH[((size_t)(n * 4 + c)) * 256 + h] = hv;
      hsum += hv;
    }
    ACAT[(size_t)n * 512 + h] = hsum;
    ACAT[(size_t)n * 512 + 256 + h] = xn[((size_t)(n * 64 + mm)) * 256 + h];
  }
}

// ---------------------------------------------------------------------------
// Graph kernels
// ---------------------------------------------------------------------------
__global__ __launch_bounds__(256) void k_edge_deg(const int* __restrict__ edges,
                                                  int* __restrict__ deg, int E) {
  int i = blockIdx.x * 256 + threadIdx.x;
  if (i < E) {
    atomicAdd(&deg[edges[2 * i]], 1);
    atomicAdd(&deg[edges[2 * i + 1]], 1);
  }
}

__global__ __launch_bounds__(256) void k_nei(const int* __restrict__ edges,
                                             const float* __restrict__ x,
                                             float* __restrict__ nei_sum) {
  int e = blockIdx.x, h = threadIdx.x;
  int a = edges[2 * e], b = edges[2 * e + 1];
  atomicAdd(&nei_sum[(size_t)a * 256 + h], x[(size_t)b * 256 + h]);
  atomicAdd(&nei_sum[(size_t)b * 256 + h], x[(size_t)a * 256 + h]);
}

__global__ __launch_bounds__(256) void k_xcat(const float* __restrict__ x,
                                              const float* __restrict__ nei_sum,
                                              const int* __restrict__ deg,
                                              float* __restrict__ xcat) {
  int n = blockIdx.x, h = threadIdx.x;
  xcat[(size_t)n * 512 + h] = x[(size_t)n * 256 + h];
  float d = fmaxf((float)deg[n], 1.f);
  xcat[(size_t)n * 512 + 256 + h] = nei_sum[(size_t)n * 256 + h] / d;
}

__global__ __launch_bounds__(256) void k_spmm_self(const float* __restrict__ y,
                                                   const int* __restrict__ deg,
                                                   float* __restrict__ ob) {
  int n = blockIdx.x, h = threadIdx.x;
  float dis2 = 1.f / (float)(deg[n] + 1);
  ob[(size_t)n * 256 + h] = dis2 * y[(size_t)n * 256 + h];
}

__global__ __launch_bounds__(256) void k_spmm_edge(const float* __restrict__ y,
                                                   const int* __restrict__ deg,
                                                   const int* __restrict__ edges,
                                                   float* __restrict__ ob) {
  int e = blockIdx.x, h = threadIdx.x;
  int a = edges[2 * e], b = edges[2 * e + 1];
  float w = (1.f / sqrtf((float)(deg[a] + 1))) * (1.f / sqrtf((float)(deg[b] + 1)));
  atomicAdd(&ob[(size_t)a * 256 + h], w * y[(size_t)b * 256 + h]);
  atomicAdd(&ob[(size_t)b * 256 + h], w * y[(size_t)a * 256 + h]);
}

__global__ __launch_bounds__(256) void k_relu_inplace(float* __restrict__ p) {
  int i = blockIdx.x * 256 + threadIdx.x;
  p[i] = fmaxf(p[i], 0.f);
}

__global__ __launch_bounds__(256) void k_final(const float* __restrict__ h2,
                                               const float* __restrict__ w1,
                                               const float* __restrict__ b1,
                                               const float* __restrict__ w2,
                                               const float* __restrict__ b2,
                                               float* __restrict__ outp) {
  __shared__ float gv[512];
  __shared__ float zz[256];
  int tid = threadIdx.x;
  float mn = 0.f, mx = -INFINITY;
  for (int n = 0; n < 512; ++n) {
    float v = h2[(size_t)n * 256 + tid];
    mn += v;
    mx = fmaxf(mx, v);
  }
  gv[tid] = mn / 512.f;
  gv[256 + tid] = mx;
  __syncthreads();
  float acc = b1[tid];
  for (int k = 0; k < 512; ++k) acc += gv[k] * w1[(size_t)tid * 512 + k];
  zz[tid] = fmaxf(acc, 0.f) * w2[tid];
  __syncthreads();
  for (int s = 128; s; s >>= 1) {
    if (tid < s) zz[tid] += zz[tid + s];
    __syncthreads();
  }
  if (tid == 0) outp[0] = zz[0] + b2[0];
}

// ---------------------------------------------------------------------------
// Host launch
// ---------------------------------------------------------------------------
extern "C" void kernel_launch(void* const* d_in, const int* in_sizes, int n_in,
                              void* d_out, int out_size, void* d_ws, size_t ws_size,
                              hipStream_t stream) {
  const int* seq_tokens    = (const int*)d_in[0];
  const int* ast_children  = (const int*)d_in[1];
  const void* ast_mask_raw = (const void*)d_in[2];
  const int* ast_label_ids = (const int*)d_in[3];
  const int* ast_tok_ids   = (const int*)d_in[4];
  const int* ctx_nei       = (const int*)d_in[5];
  const int* edges         = (const int*)d_in[6];
  const float* seq_emb  = (const float*)d_in[7];
  const float* seq_wih  = (const float*)d_in[8];
  const float* seq_whh  = (const float*)d_in[9];
  const float* seq_bih  = (const float*)d_in[10];
  const float* seq_bhh  = (const float*)d_in[11];
  const float* seq_pw   = (const float*)d_in[12];
  const float* seq_pb   = (const float*)d_in[13];
  const float* ctx_wih  = (const float*)d_in[14];
  const float* ctx_whh  = (const float*)d_in[15];
  const float* ctx_bih  = (const float*)d_in[16];
  const float* ctx_bhh  = (const float*)d_in[17];
  const float* ctx_pw   = (const float*)d_in[18];
  const float* ctx_pb   = (const float*)d_in[19];
  const float* ast_label_tab = (const float*)d_in[20];
  const float* ast_tok_tab   = (const float*)d_in[21];
  const float* ast_pw   = (const float*)d_in[22];
  const float* ast_pb   = (const float*)d_in[23];
  const float* tl_wiou  = (const float*)d_in[24];
  const float* tl_biou  = (const float*)d_in[25];
  const float* tl_uiou  = (const float*)d_in[26];
  const float* tl_wf    = (const float*)d_in[27];
  const float* tl_bf    = (const float*)d_in[28];
  const float* tl_uf    = (const float*)d_in[29];
  const float* fa_wih   = (const float*)d_in[30];
  const float* fa_whh   = (const float*)d_in[31];
  const float* fa_bih   = (const float*)d_in[32];
  const float* fa_bhh   = (const float*)d_in[33];
  const float* fa_aw    = (const float*)d_in[34];
  const float* fa_ab    = (const float*)d_in[35];
  const float* comb_w   = (const float*)d_in[36];
  const float* comb_b   = (const float*)d_in[37];
  const float* g1_w     = (const float*)d_in[38];
  const float* g1_b     = (const float*)d_in[39];
  const float* g2_w     = (const float*)d_in[40];
  const float* g2_b     = (const float*)d_in[41];
  const float* cls_w1   = (const float*)d_in[42];
  const float* cls_b1   = (const float*)d_in[43];
  const float* cls_w2   = (const float*)d_in[44];
  const float* cls_b2   = (const float*)d_in[45];
  float* outp = (float*)d_out;
  float* ws = (float*)d_ws;
  int E = in_sizes[6] / 2;

  // ----- workspace layout (floats) -----
  size_t off = 0;
  auto take = [&](size_t n) { size_t o = off; off += n; return o; };
  const size_t F_FEATS = take(512 * 5 * 256);
  const size_t F_X     = take(512 * 256);
  const size_t F_X2    = take(512 * 256);
  const size_t F_Y     = take(512 * 256);
  const size_t F_H1    = take(512 * 256);
  const size_t F_H2    = take(512 * 256);
  const size_t F_XCAT  = take(512 * 512);
  const size_t F_NEI   = take(512 * 256);
  const size_t F_DEG   = take(512);
  const size_t F_FLAG  = take(16);
  const size_t F_MSK   = take(512 * 64 * 4);
  const size_t F_WCOMB = take(768 * 512);
  const size_t F_IOUP  = take(8 * 512 * 768);    // 3.15M: iou k-slice partials
  const size_t F_FGP   = take(4 * 2048 * 256);   // 2.10M: fg  k-slice partials
  const size_t F_ACAT  = take(512 * 512);
  const size_t F_CHH   = take(2048 * 256);
  const size_t F_REGION = take(33554432);
  (void)ws_size;

  float* FEATS = ws + F_FEATS;
  float* X     = ws + F_X;
  float* X2    = ws + F_X2;
  float* Y     = ws + F_Y;
  float* H1    = ws + F_H1;
  float* H2    = ws + F_H2;
  float* XCAT  = ws + F_XCAT;
  float* NEI   = ws + F_NEI;
  int*   DEG   = (int*)(ws + F_DEG);
  int*   FLAG  = (int*)(ws + F_FLAG);
  int*   MSK   = (int*)(ws + F_MSK);
  float* WCOMB = ws + F_WCOMB;
  float* IOUP  = ws + F_IOUP;
  float* FGP   = ws + F_FGP;
  float* ACAT  = ws + F_ACAT;
  float* CHH   = ws + F_CHH;
  float* GI    = ws + F_REGION;                 // 25165824 (enc/ctx gi)
  float* OUT   = ws + F_REGION + 25165824;      // 8388608  (enc/ctx gru out)
  float* XN    = ws + F_REGION;                 // 8388608  (ast phase)
  float* XF    = XN + 8388608;
  float* HARR  = XF + 8388608;
  float* CARR  = HARR + 8388608;
  float* GIFA  = ws + F_REGION;                 // fa phase
  float* OUTFA = GIFA + 1966080;

  auto gemm = [&](const float* A, const int* ridx, int rstride, const float* W,
                  const float* bias, float* C, int R, int K, int J, int relu) {
    dim3 g((R / 128) * (J / 128));
    k_gemm128<<<g, 256, 0, stream>>>(A, ridx, rstride, W, bias, C, R, K, J, relu);
  };

  // ---- prep ----
  k_build_wcomb<<<1536, 256, 0, stream>>>(tl_uiou, tl_wiou, WCOMB);
  k_zero_misc<<<512, 256, 0, stream>>>(NEI, DEG, FLAG);
  k_mask_detect<<<128, 256, 0, stream>>>((const unsigned*)ast_mask_raw, FLAG);
  k_mask_convert<<<512, 256, 0, stream>>>(ast_mask_raw, FLAG, MSK);

  // ---- 3 sequence encoders: slots 0 (stmt), 2 (varn), 3 (vart) ----
  const int slot_of[3] = {0, 2, 3};
  for (int e = 0; e < 3; ++e) {
    gemm(seq_emb + (size_t)e * 50000 * 256, seq_tokens + (size_t)e * 32768, 256,
         seq_wih + (size_t)e * 768 * 256, seq_bih + (size_t)e * 768, GI,
         32768, 256, 768, 0);
    k_gru3<<<dim3(128, 2), 512, 0, stream>>>(GI, seq_whh + (size_t)e * 2 * 384 * 128,
                                             seq_bhh + (size_t)e * 768, OUT, 64);
    k_attn_pool<<<512, 256, 0, stream>>>(OUT, 64 * 256, 256, OUT, 64 * 256, 256,
                                         seq_pw + e * 256, seq_pb + e,
                                         FEATS + slot_of[e] * 256, 1280, 64);
  }

  // ---- ctx encoder (needs stmt slot0): slot 4 ----
  gemm(FEATS, ctx_nei, 1280, ctx_wih, ctx_bih, GI, 4096, 256, 768, 0);
  k_gru3<<<dim3(128, 2), 512, 0, stream>>>(GI, ctx_whh, ctx_bhh, OUT, 8);
  k_attn_pool<<<512, 256, 0, stream>>>(OUT, 8 * 256, 256, OUT, 8 * 256, 256,
                                       ctx_pw, ctx_pb, FEATS + 4 * 256, 1280, 8);

  // ---- AST TreeLSTM: slot 1 ----
  k_xn<<<32768, 256, 0, stream>>>(ast_label_tab, ast_tok_tab, ast_label_ids,
                                  ast_tok_ids, XN);
  gemm(XN, nullptr, 256, tl_wf, tl_bf, XF, 32768, 256, 256, 0);
  k_tl_init<<<512, 256, 0, stream>>>(XN, ACAT, CHH);
  for (int m = 0; m < 64; ++m) {
    k_tl_gemm3<<<320, 256, 0, stream>>>(ACAT, CHH, WCOMB, tl_uf, IOUP, FGP);
    k_tl_combine3<<<512, 256, 0, stream>>>(IOUP, FGP, tl_biou, XF, XN,
                                           ast_children, MSK, HARR, CARR,
                                           ACAT, CHH, m);
  }
  k_attn_pool<<<512, 256, 0, stream>>>(HARR, 256, 512 * 256, HARR, 256, 512 * 256,
                                       ast_pw, ast_pb, FEATS + 1 * 256, 1280, 64);

  // ---- feature-attention biGRU over the 5 slots -> x ----
  gemm(FEATS, nullptr, 256, fa_wih, fa_bih, GIFA, 2560, 256, 768, 0);
  k_gru3<<<dim3(128, 2), 512, 0, stream>>>(GIFA, fa_whh, fa_bhh, OUTFA, 5);
  k_attn_pool<<<512, 256, 0, stream>>>(OUTFA, 5 * 256, 256, FEATS, 1280, 256,
                                       fa_aw, fa_ab, X, 256, 5);

  // ---- graph section ----
  k_edge_deg<<<(E + 255) / 256, 256, 0, stream>>>(edges, DEG, E);
  k_nei<<<E, 256, 0, stream>>>(edges, X, NEI);
  k_xcat<<<512, 256, 0, stream>>>(X, NEI, DEG, XCAT);
  gemm(XCAT, nullptr, 512, comb_w, comb_b, X2, 512, 512, 256, 1);
  gemm(X2, nullptr, 256, g1_w, g1_b, Y, 512, 256, 256, 0);
  k_spmm_self<<<512, 256, 0, stream>>>(Y, DEG, H1);
  k_spmm_edge<<<E, 256, 0, stream>>>(Y, DEG, edges, H1);
  k_relu_inplace<<<512, 256, 0, stream>>>(H1);
  gemm(H1, nullptr, 256, g2_w, g2_b, Y, 512, 256, 256, 0);
  k_spmm_self<<<512, 256, 0, stream>>>(Y, DEG, H2);
  k_spmm_edge<<<E, 256, 0, stream>>>(Y, DEG, edges, H2);
  k_relu_inplace<<<512, 256, 0, stream>>>(H2);
  k_final<<<1, 256, 0, stream>>>(H2, cls_w1, cls_b1, cls_w2, cls_b2, outp);
}

// Round 4
// 2989.865 us; speedup vs baseline: 2.9535x; 1.2905x over previous
//
#include <hip/hip_runtime.h>
#include <cmath>

// ---------------------------------------------------------------------------
// Model dims: H=256 HID=128 V=50000 LV=200 N=512 L=64 M=64 C=4 T=8 K=8
// ---------------------------------------------------------------------------

__device__ __forceinline__ float sigf(float x) { return 1.f / (1.f + expf(-x)); }

// ---------------------------------------------------------------------------
// WXALL weights: [wiou (768) | wf (256)] rows x 256, bias [biou | bf]
// ---------------------------------------------------------------------------
__global__ __launch_bounds__(256) void k_build_wx(const float* __restrict__ wiou,
                                                  const float* __restrict__ wf,
                                                  const float* __restrict__ biou,
                                                  const float* __restrict__ bf,
                                                  float* __restrict__ w,
                                                  float* __restrict__ b) {
  int i = blockIdx.x * 256 + threadIdx.x;
  if (i < 1024 * 256) {
    int j = i >> 8, k = i & 255;
    w[i] = (j < 768) ? wiou[j * 256 + k] : wf[(j - 768) * 256 + k];
  }
  if (i < 1024) b[i] = (i < 768) ? biou[i] : bf[i - 768];
}

// WPROJ: [uiou (768) | uf (256)] rows x 256
__global__ __launch_bounds__(256) void k_build_wproj(const float* __restrict__ uiou,
                                                     const float* __restrict__ uf,
                                                     float* __restrict__ w) {
  int i = blockIdx.x * 256 + threadIdx.x;
  if (i >= 1024 * 256) return;
  int j = i >> 8, k = i & 255;
  w[i] = (j < 768) ? uiou[j * 256 + k] : uf[(j - 768) * 256 + k];
}

__global__ __launch_bounds__(256) void k_zero_misc(float* __restrict__ nei_sum,
                                                   int* __restrict__ deg,
                                                   int* __restrict__ flag) {
  int i = blockIdx.x * 256 + threadIdx.x;
  if (i < 512 * 256) nei_sum[i] = 0.f;
  if (i < 512) deg[i] = 0;
  if (i == 0) *flag = 0;
}

// bool-mask dtype detector (int32 vs byte-packed)
__global__ __launch_bounds__(256) void k_mask_detect(const unsigned* __restrict__ raw,
                                                     int* __restrict__ flag) {
  int i = blockIdx.x * 256 + threadIdx.x;
  if (i < 32768) {
    if (raw[i] > 1u) atomicOr(flag, 1);
  }
}

__global__ __launch_bounds__(256) void k_mask_convert(const void* __restrict__ raw,
                                                      const int* __restrict__ flag,
                                                      int* __restrict__ msk) {
  int i = blockIdx.x * 256 + threadIdx.x;
  if (i >= 512 * 64 * 4) return;
  int v;
  if (*flag) v = ((const unsigned char*)raw)[i] != 0;
  else       v = ((const int*)raw)[i] != 0;
  msk[i] = v;
}

// ---------------------------------------------------------------------------
// Generic fp32 GEMM: 128x128 tile, 256 threads, 8x8 micro as 2x2 quads of
// 4x4 (conflict-free LDS reads: a-reads broadcast, b-reads 2-way), K chunk 16.
// ---------------------------------------------------------------------------
__global__ __launch_bounds__(256) void k_gemm128(const float* __restrict__ A,
                                                 const int* __restrict__ ridx,
                                                 int rstride,
                                                 const float* __restrict__ W,
                                                 const float* __restrict__ bias,
                                                 float* __restrict__ C,
                                                 int R, int K, int J, int relu) {
  __shared__ float As[16][132];
  __shared__ float Ws[16][132];
  int njt = J >> 7;
  int rt = blockIdx.x / njt;
  int jt = blockIdx.x % njt;
  int tid = threadIdx.x;
  int tx = tid & 15, ty = tid >> 4;

  int row2 = tid >> 1;         // 0..127
  int kq = (tid & 1) * 4;      // 0 or 4 (loads at kq and kq+8)
  int gr = rt * 128 + row2;
  const float* arow = A + (size_t)(ridx ? ridx[gr] : gr) * rstride;
  const float* wrow = W + (size_t)(jt * 128 + row2) * K;

  float acc[8][8];
#pragma unroll
  for (int i = 0; i < 8; ++i)
#pragma unroll
    for (int j = 0; j < 8; ++j) acc[i][j] = 0.f;

  for (int k0 = 0; k0 < K; k0 += 16) {
    float4 av0 = *(const float4*)(arow + k0 + kq);
    float4 av1 = *(const float4*)(arow + k0 + kq + 8);
    float4 wv0 = *(const float4*)(wrow + k0 + kq);
    float4 wv1 = *(const float4*)(wrow + k0 + kq + 8);
    __syncthreads();
    As[kq + 0][row2] = av0.x; As[kq + 1][row2] = av0.y;
    As[kq + 2][row2] = av0.z; As[kq + 3][row2] = av0.w;
    As[kq + 8][row2] = av1.x; As[kq + 9][row2] = av1.y;
    As[kq + 10][row2] = av1.z; As[kq + 11][row2] = av1.w;
    Ws[kq + 0][row2] = wv0.x; Ws[kq + 1][row2] = wv0.y;
    Ws[kq + 2][row2] = wv0.z; Ws[kq + 3][row2] = wv0.w;
    Ws[kq + 8][row2] = wv1.x; Ws[kq + 9][row2] = wv1.y;
    Ws[kq + 10][row2] = wv1.z; Ws[kq + 11][row2] = wv1.w;
    __syncthreads();
#pragma unroll
    for (int kk = 0; kk < 16; ++kk) {
      float a[8], b[8];
      *(float4*)&a[0] = *(const float4*)&As[kk][ty * 4];
      *(float4*)&a[4] = *(const float4*)&As[kk][64 + ty * 4];
      *(float4*)&b[0] = *(const float4*)&Ws[kk][tx * 4];
      *(float4*)&b[4] = *(const float4*)&Ws[kk][64 + tx * 4];
#pragma unroll
      for (int i = 0; i < 8; ++i)
#pragma unroll
        for (int j = 0; j < 8; ++j) acc[i][j] += a[i] * b[j];
    }
  }

  int col0 = jt * 128 + tx * 4;
  int col1 = jt * 128 + 64 + tx * 4;
  float b0[4], b1[4];
#pragma unroll
  for (int j = 0; j < 4; ++j) {
    b0[j] = bias ? bias[col0 + j] : 0.f;
    b1[j] = bias ? bias[col1 + j] : 0.f;
  }
#pragma unroll
  for (int i = 0; i < 8; ++i) {
    int row = rt * 128 + ((i < 4) ? (ty * 4 + i) : (64 + ty * 4 + i - 4));
    float v0[4], v1[4];
#pragma unroll
    for (int j = 0; j < 4; ++j) {
      float x0 = acc[i][j] + b0[j];
      float x1 = acc[i][j + 4] + b1[j];
      if (relu) { x0 = fmaxf(x0, 0.f); x1 = fmaxf(x1, 0.f); }
      v0[j] = x0; v1[j] = x1;
    }
    *(float4*)(C + (size_t)row * J + col0) = *(float4*)v0;
    *(float4*)(C + (size_t)row * J + col1) = *(float4*)v1;
  }
}

// ---------------------------------------------------------------------------
// GRU recurrence v3 (unchanged from round 3)
// ---------------------------------------------------------------------------
__global__ __launch_bounds__(512, 2) void k_gru3(const float* __restrict__ gi,
                                                 const float* __restrict__ whh,
                                                 const float* __restrict__ bhh,
                                                 float* __restrict__ out,
                                                 int L) {
  __shared__ float hs[4][132];
  __shared__ float parts[4][8][388];
  int tid = threadIdx.x;
  int d = blockIdx.y;
  int n0 = blockIdx.x * 4;
  int ks = tid >> 6;
  int rg = tid & 63;
  int kb = ks * 16;
  const float* wbase = whh + (size_t)d * 384 * 128;

  float4 w4[6][4];
#pragma unroll
  for (int r = 0; r < 6; ++r) {
    const float* wr = wbase + (size_t)(r * 64 + rg) * 128 + kb;
#pragma unroll
    for (int q = 0; q < 4; ++q) w4[r][q] = ((const float4*)wr)[q];
  }

  int sg = tid >> 7, jg = tid & 127;
  const float* bh = bhh + d * 384;
  float br = bh[jg], bz = bh[128 + jg], bn = bh[256 + jg];

  for (int i = tid; i < 4 * 132; i += 512) ((float*)hs)[i] = 0.f;
  __syncthreads();

  int t = d ? (L - 1) : 0;
  int dt = d ? -1 : 1;

  for (int step = 0; step < L; ++step, t += dt) {
    const float* g = gi + (size_t)((n0 + sg) * L + t) * 768 + d * 384;
    float pgr = g[jg], pgz = g[128 + jg], pgn = g[256 + jg];

    float acc[4][6];
#pragma unroll
    for (int s = 0; s < 4; ++s)
#pragma unroll
      for (int r = 0; r < 6; ++r) acc[s][r] = 0.f;
#pragma unroll
    for (int s = 0; s < 4; ++s) {
#pragma unroll
      for (int q = 0; q < 4; ++q) {
        float4 hv = *(const float4*)&hs[s][kb + q * 4];
#pragma unroll
        for (int r = 0; r < 6; ++r) {
          acc[s][r] += w4[r][q].x * hv.x + w4[r][q].y * hv.y +
                       w4[r][q].z * hv.z + w4[r][q].w * hv.w;
        }
      }
    }
#pragma unroll
    for (int s = 0; s < 4; ++s)
#pragma unroll
      for (int r = 0; r < 6; ++r) parts[s][ks][r * 64 + rg] = acc[s][r];
    __syncthreads();
    {
      float sr = 0.f, sz = 0.f, sn = 0.f;
#pragma unroll
      for (int k = 0; k < 8; ++k) {
        sr += parts[sg][k][jg];
        sz += parts[sg][k][128 + jg];
        sn += parts[sg][k][256 + jg];
      }
      float r = sigf(pgr + sr + br);
      float z = sigf(pgz + sz + bz);
      float nn = tanhf(pgn + r * (sn + bn));
      float hold = hs[sg][jg];
      float hnew = (1.f - z) * nn + z * hold;
      hs[sg][jg] = hnew;
      out[(size_t)((n0 + sg) * L + t) * 256 + d * 128 + jg] = hnew;
    }
    __syncthreads();
  }
}

// ---------------------------------------------------------------------------
// Attention pool (one block per n)
// ---------------------------------------------------------------------------
__global__ __launch_bounds__(256) void k_attn_pool(const float* __restrict__ score_src,
                                                   int s_ns, int s_ls,
                                                   const float* __restrict__ val_src,
                                                   int v_ns, int v_ls,
                                                   const float* __restrict__ w,
                                                   const float* __restrict__ bptr,
                                                   float* __restrict__ dst,
                                                   int dst_stride, int L) {
  __shared__ float wts[64];
  int n = blockIdx.x;
  int tid = threadIdx.x;
  if (tid < 64) {
    float a = -INFINITY;
    if (tid < L) {
      const float* row = score_src + (size_t)n * s_ns + (size_t)tid * s_ls;
      float s = bptr[0];
      for (int h = 0; h < 256; h += 4) {
        float4 v = *(const float4*)(row + h);
        float4 wv = *(const float4*)(w + h);
        s += v.x * wv.x + v.y * wv.y + v.z * wv.z + v.w * wv.w;
      }
      a = s;
    }
    float mx = a;
#pragma unroll
    for (int off = 32; off; off >>= 1) mx = fmaxf(mx, __shfl_xor(mx, off));
    float e = (tid < L) ? expf(a - mx) : 0.f;
    float ss = e;
#pragma unroll
    for (int off = 32; off; off >>= 1) ss += __shfl_xor(ss, off);
    if (tid < L) wts[tid] = e / ss;
  }
  __syncthreads();
  float acc = 0.f;
  for (int l = 0; l < L; ++l)
    acc += wts[l] * val_src[(size_t)n * v_ns + (size_t)l * v_ls + tid];
  dst[(size_t)n * dst_stride + tid] = acc;
}

// ---------------------------------------------------------------------------
// xn[n][m][h] = 0.5*label_tab[lbl][h] + (1/16)*sum_t tok_tab[id][h]
// ---------------------------------------------------------------------------
__global__ __launch_bounds__(256) void k_xn(const float* __restrict__ label_tab,
                                            const float* __restrict__ tok_tab,
                                            const int* __restrict__ lbl_ids,
                                            const int* __restrict__ tok_ids,
                                            float* __restrict__ xn) {
  int nm = blockIdx.x;
  int h = threadIdx.x;
  const int* tids = tok_ids + (size_t)nm * 8;
  float s = 0.f;
#pragma unroll
  for (int t = 0; t < 8; ++t) s += tok_tab[(size_t)tids[t] * 256 + h];
  xn[(size_t)nm * 256 + h] = 0.5f * label_tab[(size_t)lbl_ids[nm] * 256 + h] + 0.0625f * s;
}

// ---------------------------------------------------------------------------
// TreeLSTM combine (step m): gates from XWALL + gathered HU; writes h_m, c_m.
//   HU[m'][n][j]: j<768 -> h@uiou.T ; j>=768 -> h@uf.T
//   XWALL[nm][j]: j<768 -> x@wiou.T + biou ; j>=768 -> x@wf.T + bf
// ---------------------------------------------------------------------------
__global__ __launch_bounds__(256) void k_tl_combine4(const float* __restrict__ HU,
                                                     const float* __restrict__ XWALL,
                                                     const int* __restrict__ ch,
                                                     const int* __restrict__ msk,
                                                     float* __restrict__ h_arr,
                                                     float* __restrict__ c_arr,
                                                     int m) {
  int n = blockIdx.x, h = threadIdx.x;
  const float* xw = XWALL + ((size_t)(n * 64 + m)) * 1024;
  float si = xw[h], so = xw[256 + h], su = xw[512 + h], xfv = xw[768 + h];
  const int* chp = ch + ((size_t)(n * 64 + m)) * 4;
  const int* mkp = msk + ((size_t)(n * 64 + m)) * 4;
  float cs = 0.f;
#pragma unroll
  for (int c = 0; c < 4; ++c) {
    if (mkp[c]) {
      int cc = chp[c];
      const float* hu = HU + ((size_t)cc * 512 + n) * 1024;
      si += hu[h];
      so += hu[256 + h];
      su += hu[512 + h];
      float fg = sigf(xfv + hu[768 + h]);
      cs += fg * c_arr[((size_t)cc * 512 + n) * 256 + h];
    }
  }
  float iv = sigf(si), ov = sigf(so), uv = tanhf(su);
  float cn = iv * uv + cs;
  float hn = ov * tanhf(cn);
  h_arr[((size_t)m * 512 + n) * 256 + h] = hn;
  c_arr[((size_t)m * 512 + n) * 256 + h] = cn;
}

// ---------------------------------------------------------------------------
// TreeLSTM projection (step m): HU[m] = h_m @ WPROJ.T  (512x1024, K=256)
//   64x64 tiles, 128 blocks, 4x4 micro, K chunk 16.
// ---------------------------------------------------------------------------
__global__ __launch_bounds__(256) void k_tl_proj(const float* __restrict__ h_arr,
                                                 const float* __restrict__ WPROJ,
                                                 float* __restrict__ HU, int m) {
  __shared__ float As[16][68];
  __shared__ float Ws[16][68];
  int b = blockIdx.x;         // 128
  int rt = b >> 4, jt = b & 15;
  int tid = threadIdx.x;
  int tx = tid & 15, ty = tid >> 4;
  int row = tid >> 2;          // 0..63
  int kq = (tid & 3) * 4;      // 0,4,8,12

  const float* arow = h_arr + (size_t)(m * 512 + rt * 64 + row) * 256;
  const float* wrow = WPROJ + (size_t)(jt * 64 + row) * 256;

  float acc[4][4];
#pragma unroll
  for (int i = 0; i < 4; ++i)
#pragma unroll
    for (int j = 0; j < 4; ++j) acc[i][j] = 0.f;

  for (int k0 = 0; k0 < 256; k0 += 16) {
    float4 av = *(const float4*)(arow + k0 + kq);
    float4 wv = *(const float4*)(wrow + k0 + kq);
    __syncthreads();
    As[kq + 0][row] = av.x; As[kq + 1][row] = av.y;
    As[kq + 2][row] = av.z; As[kq + 3][row] = av.w;
    Ws[kq + 0][row] = wv.x; Ws[kq + 1][row] = wv.y;
    Ws[kq + 2][row] = wv.z; Ws[kq + 3][row] = wv.w;
    __syncthreads();
#pragma unroll
    for (int kk = 0; kk < 16; ++kk) {
      float a[4], bv[4];
      *(float4*)&a[0] = *(const float4*)&As[kk][ty * 4];
      *(float4*)&bv[0] = *(const float4*)&Ws[kk][tx * 4];
#pragma unroll
      for (int i = 0; i < 4; ++i)
#pragma unroll
        for (int j = 0; j < 4; ++j) acc[i][j] += a[i] * bv[j];
    }
  }

  float* outb = HU + (size_t)m * 512 * 1024;
#pragma unroll
  for (int i = 0; i < 4; ++i) {
    float* crow = outb + (size_t)(rt * 64 + ty * 4 + i) * 1024 + jt * 64 + tx * 4;
    *(float4*)crow = *(float4*)&acc[i][0];
  }
}

// ---------------------------------------------------------------------------
// Graph kernels
// ---------------------------------------------------------------------------
__global__ __launch_bounds__(256) void k_edge_deg(const int* __restrict__ edges,
                                                  int* __restrict__ deg, int E) {
  int i = blockIdx.x * 256 + threadIdx.x;
  if (i < E) {
    atomicAdd(&deg[edges[2 * i]], 1);
    atomicAdd(&deg[edges[2 * i + 1]], 1);
  }
}

__global__ __launch_bounds__(256) void k_nei(const int* __restrict__ edges,
                                             const float* __restrict__ x,
                                             float* __restrict__ nei_sum) {
  int e = blockIdx.x, h = threadIdx.x;
  int a = edges[2 * e], b = edges[2 * e + 1];
  atomicAdd(&nei_sum[(size_t)a * 256 + h], x[(size_t)b * 256 + h]);
  atomicAdd(&nei_sum[(size_t)b * 256 + h], x[(size_t)a * 256 + h]);
}

__global__ __launch_bounds__(256) void k_xcat(const float* __restrict__ x,
                                              const float* __restrict__ nei_sum,
                                              const int* __restrict__ deg,
                                              float* __restrict__ xcat) {
  int n = blockIdx.x, h = threadIdx.x;
  xcat[(size_t)n * 512 + h] = x[(size_t)n * 256 + h];
  float d = fmaxf((float)deg[n], 1.f);
  xcat[(size_t)n * 512 + 256 + h] = nei_sum[(size_t)n * 256 + h] / d;
}

__global__ __launch_bounds__(256) void k_spmm_self(const float* __restrict__ y,
                                                   const int* __restrict__ deg,
                                                   float* __restrict__ ob) {
  int n = blockIdx.x, h = threadIdx.x;
  float dis2 = 1.f / (float)(deg[n] + 1);
  ob[(size_t)n * 256 + h] = dis2 * y[(size_t)n * 256 + h];
}

__global__ __launch_bounds__(256) void k_spmm_edge(const float* __restrict__ y,
                                                   const int* __restrict__ deg,
                                                   const int* __restrict__ edges,
                                                   float* __restrict__ ob) {
  int e = blockIdx.x, h = threadIdx.x;
  int a = edges[2 * e], b = edges[2 * e + 1];
  float w = (1.f / sqrtf((float)(deg[a] + 1))) * (1.f / sqrtf((float)(deg[b] + 1)));
  atomicAdd(&ob[(size_t)a * 256 + h], w * y[(size_t)b * 256 + h]);
  atomicAdd(&ob[(size_t)b * 256 + h], w * y[(size_t)a * 256 + h]);
}

__global__ __launch_bounds__(256) void k_relu_inplace(float* __restrict__ p) {
  int i = blockIdx.x * 256 + threadIdx.x;
  p[i] = fmaxf(p[i], 0.f);
}

__global__ __launch_bounds__(256) void k_final(const float* __restrict__ h2,
                                               const float* __restrict__ w1,
                                               const float* __restrict__ b1,
                                               const float* __restrict__ w2,
                                               const float* __restrict__ b2,
                                               float* __restrict__ outp) {
  __shared__ float gv[512];
  __shared__ float zz[256];
  int tid = threadIdx.x;
  float mn = 0.f, mx = -INFINITY;
  for (int n = 0; n < 512; ++n) {
    float v = h2[(size_t)n * 256 + tid];
    mn += v;
    mx = fmaxf(mx, v);
  }
  gv[tid] = mn / 512.f;
  gv[256 + tid] = mx;
  __syncthreads();
  float acc = b1[tid];
  for (int k = 0; k < 512; ++k) acc += gv[k] * w1[(size_t)tid * 512 + k];
  zz[tid] = fmaxf(acc, 0.f) * w2[tid];
  __syncthreads();
  for (int s = 128; s; s >>= 1) {
    if (tid < s) zz[tid] += zz[tid + s];
    __syncthreads();
  }
  if (tid == 0) outp[0] = zz[0] + b2[0];
}

// ---------------------------------------------------------------------------
// Host launch
// ---------------------------------------------------------------------------
extern "C" void kernel_launch(void* const* d_in, const int* in_sizes, int n_in,
                              void* d_out, int out_size, void* d_ws, size_t ws_size,
                              hipStream_t stream) {
  const int* seq_tokens    = (const int*)d_in[0];
  const int* ast_children  = (const int*)d_in[1];
  const void* ast_mask_raw = (const void*)d_in[2];
  const int* ast_label_ids = (const int*)d_in[3];
  const int* ast_tok_ids   = (const int*)d_in[4];
  const int* ctx_nei       = (const int*)d_in[5];
  const int* edges         = (const int*)d_in[6];
  const float* seq_emb  = (const float*)d_in[7];
  const float* seq_wih  = (const float*)d_in[8];
  const float* seq_whh  = (const float*)d_in[9];
  const float* seq_bih  = (const float*)d_in[10];
  const float* seq_bhh  = (const float*)d_in[11];
  const float* seq_pw   = (const float*)d_in[12];
  const float* seq_pb   = (const float*)d_in[13];
  const float* ctx_wih  = (const float*)d_in[14];
  const float* ctx_whh  = (const float*)d_in[15];
  const float* ctx_bih  = (const float*)d_in[16];
  const float* ctx_bhh  = (const float*)d_in[17];
  const float* ctx_pw   = (const float*)d_in[18];
  const float* ctx_pb   = (const float*)d_in[19];
  const float* ast_label_tab = (const float*)d_in[20];
  const float* ast_tok_tab   = (const float*)d_in[21];
  const float* ast_pw   = (const float*)d_in[22];
  const float* ast_pb   = (const float*)d_in[23];
  const float* tl_wiou  = (const float*)d_in[24];
  const float* tl_biou  = (const float*)d_in[25];
  const float* tl_uiou  = (const float*)d_in[26];
  const float* tl_wf    = (const float*)d_in[27];
  const float* tl_bf    = (const float*)d_in[28];
  const float* tl_uf    = (const float*)d_in[29];
  const float* fa_wih   = (const float*)d_in[30];
  const float* fa_whh   = (const float*)d_in[31];
  const float* fa_bih   = (const float*)d_in[32];
  const float* fa_bhh   = (const float*)d_in[33];
  const float* fa_aw    = (const float*)d_in[34];
  const float* fa_ab    = (const float*)d_in[35];
  const float* comb_w   = (const float*)d_in[36];
  const float* comb_b   = (const float*)d_in[37];
  const float* g1_w     = (const float*)d_in[38];
  const float* g1_b     = (const float*)d_in[39];
  const float* g2_w     = (const float*)d_in[40];
  const float* g2_b     = (const float*)d_in[41];
  const float* cls_w1   = (const float*)d_in[42];
  const float* cls_b1   = (const float*)d_in[43];
  const float* cls_w2   = (const float*)d_in[44];
  const float* cls_b2   = (const float*)d_in[45];
  float* outp = (float*)d_out;
  float* ws = (float*)d_ws;
  int E = in_sizes[6] / 2;

  // ----- workspace layout (floats) -----
  size_t off = 0;
  auto take = [&](size_t n) { size_t o = off; off += n; return o; };
  const size_t F_FEATS = take(512 * 5 * 256);
  const size_t F_X     = take(512 * 256);
  const size_t F_X2    = take(512 * 256);
  const size_t F_Y     = take(512 * 256);
  const size_t F_H1    = take(512 * 256);
  const size_t F_H2    = take(512 * 256);
  const size_t F_XCAT  = take(512 * 512);
  const size_t F_NEI   = take(512 * 256);
  const size_t F_DEG   = take(512);
  const size_t F_FLAG  = take(16);
  const size_t F_MSK   = take(512 * 64 * 4);
  const size_t F_WXW   = take(1024 * 256);
  const size_t F_WXB   = take(1024);
  const size_t F_WPROJ = take(1024 * 256);
  const size_t F_REGION = take(83886080);  // shared phase region
  (void)ws_size;

  float* FEATS = ws + F_FEATS;
  float* X     = ws + F_X;
  float* X2    = ws + F_X2;
  float* Y     = ws + F_Y;
  float* H1    = ws + F_H1;
  float* H2    = ws + F_H2;
  float* XCAT  = ws + F_XCAT;
  float* NEI   = ws + F_NEI;
  int*   DEG   = (int*)(ws + F_DEG);
  int*   FLAG  = (int*)(ws + F_FLAG);
  int*   MSK   = (int*)(ws + F_MSK);
  float* WXW   = ws + F_WXW;
  float* WXB   = ws + F_WXB;
  float* WPROJ = ws + F_WPROJ;
  float* REG   = ws + F_REGION;
  // enc phase
  float* GI    = REG;                     // 25165824
  float* OUT   = REG + 25165824;          // 8388608
  // TL phase
  float* XWALL = REG;                     // 33554432 (32768 x 1024)
  float* HARR  = REG + 33554432;          // 8388608
  float* CARR  = REG + 41943040;          // 8388608
  float* HU    = REG + 50331648;          // 33554432 (64 x 512 x 1024)
  float* XN    = HU;                      // 8388608, aliased (dead before HU writes)
  // fa phase
  float* GIFA  = REG;                     // 1966080
  float* OUTFA = GIFA + 1966080;

  auto gemm = [&](const float* A, const int* ridx, int rstride, const float* W,
                  const float* bias, float* C, int R, int K, int J, int relu) {
    dim3 g((R / 128) * (J / 128));
    k_gemm128<<<g, 256, 0, stream>>>(A, ridx, rstride, W, bias, C, R, K, J, relu);
  };

  // ---- prep ----
  k_build_wx<<<1024, 256, 0, stream>>>(tl_wiou, tl_wf, tl_biou, tl_bf, WXW, WXB);
  k_build_wproj<<<1024, 256, 0, stream>>>(tl_uiou, tl_uf, WPROJ);
  k_zero_misc<<<512, 256, 0, stream>>>(NEI, DEG, FLAG);
  k_mask_detect<<<128, 256, 0, stream>>>((const unsigned*)ast_mask_raw, FLAG);
  k_mask_convert<<<512, 256, 0, stream>>>(ast_mask_raw, FLAG, MSK);

  // ---- 3 sequence encoders: slots 0 (stmt), 2 (varn), 3 (vart) ----
  const int slot_of[3] = {0, 2, 3};
  for (int e = 0; e < 3; ++e) {
    gemm(seq_emb + (size_t)e * 50000 * 256, seq_tokens + (size_t)e * 32768, 256,
         seq_wih + (size_t)e * 768 * 256, seq_bih + (size_t)e * 768, GI,
         32768, 256, 768, 0);
    k_gru3<<<dim3(128, 2), 512, 0, stream>>>(GI, seq_whh + (size_t)e * 2 * 384 * 128,
                                             seq_bhh + (size_t)e * 768, OUT, 64);
    k_attn_pool<<<512, 256, 0, stream>>>(OUT, 64 * 256, 256, OUT, 64 * 256, 256,
                                         seq_pw + e * 256, seq_pb + e,
                                         FEATS + slot_of[e] * 256, 1280, 64);
  }

  // ---- ctx encoder (needs stmt slot0): slot 4 ----
  gemm(FEATS, ctx_nei, 1280, ctx_wih, ctx_bih, GI, 4096, 256, 768, 0);
  k_gru3<<<dim3(128, 2), 512, 0, stream>>>(GI, ctx_whh, ctx_bhh, OUT, 8);
  k_attn_pool<<<512, 256, 0, stream>>>(OUT, 8 * 256, 256, OUT, 8 * 256, 256,
                                       ctx_pw, ctx_pb, FEATS + 4 * 256, 1280, 8);

  // ---- AST TreeLSTM: slot 1 ----
  k_xn<<<32768, 256, 0, stream>>>(ast_label_tab, ast_tok_tab, ast_label_ids,
                                  ast_tok_ids, XN);
  gemm(XN, nullptr, 256, WXW, WXB, XWALL, 32768, 256, 1024, 0);
  for (int m = 0; m < 64; ++m) {
    k_tl_combine4<<<512, 256, 0, stream>>>(HU, XWALL, ast_children, MSK,
                                           HARR, CARR, m);
    if (m < 63)
      k_tl_proj<<<128, 256, 0, stream>>>(HARR, WPROJ, HU, m);
  }
  k_attn_pool<<<512, 256, 0, stream>>>(HARR, 256, 512 * 256, HARR, 256, 512 * 256,
                                       ast_pw, ast_pb, FEATS + 1 * 256, 1280, 64);

  // ---- feature-attention biGRU over the 5 slots -> x ----
  gemm(FEATS, nullptr, 256, fa_wih, fa_bih, GIFA, 2560, 256, 768, 0);
  k_gru3<<<dim3(128, 2), 512, 0, stream>>>(GIFA, fa_whh, fa_bhh, OUTFA, 5);
  k_attn_pool<<<512, 256, 0, stream>>>(OUTFA, 5 * 256, 256, FEATS, 1280, 256,
                                       fa_aw, fa_ab, X, 256, 5);

  // ---- graph section ----
  k_edge_deg<<<(E + 255) / 256, 256, 0, stream>>>(edges, DEG, E);
  k_nei<<<E, 256, 0, stream>>>(edges, X, NEI);
  k_xcat<<<512, 256, 0, stream>>>(X, NEI, DEG, XCAT);
  gemm(XCAT, nullptr, 512, comb_w, comb_b, X2, 512, 512, 256, 1);
  gemm(X2, nullptr, 256, g1_w, g1_b, Y, 512, 256, 256, 0);
  k_spmm_self<<<512, 256, 0, stream>>>(Y, DEG, H1);
  k_spmm_edge<<<E, 256, 0, stream>>>(Y, DEG, edges, H1);
  k_relu_inplace<<<512, 256, 0, stream>>>(H1);
  gemm(H1, nullptr, 256, g2_w, g2_b, Y, 512, 256, 256, 0);
  k_spmm_self<<<512, 256, 0, stream>>>(Y, DEG, H2);
  k_spmm_edge<<<E, 256, 0, stream>>>(Y, DEG, edges, H2);
  k_relu_inplace<<<512, 256, 0, stream>>>(H2);
  k_final<<<1, 256, 0, stream>>>(H2, cls_w1, cls_b1, cls_w2, cls_b2, outp);
}